// Round 3
// baseline (14320.992 us; speedup 1.0000x reference)
//
#include <hip/hip_runtime.h>
#include <math.h>

typedef float f32x4 __attribute__((ext_vector_type(4)));

#define T_    2048
#define DM_   2048
#define KV_   1024
#define L2T_  0.4152410118609203f     // log2(10000)/32

// ---------------------------------------------------------------------------
// Naive f32 QKV GEMM: C = A(4096x2048) @ B(2048x3072). cols<2048 -> qy (f32,
// stride 2048), cols>=2048 -> kv (f32, stride 1024). 64x64 tile, 4x4/thread.
// ---------------------------------------------------------------------------
__global__ __launch_bounds__(256) void qkv_gemm_naive(
    const float* __restrict__ A, const float* __restrict__ B,
    float* __restrict__ Cq, float* __restrict__ Ckv, int M, int N, int K){
  __shared__ float As[64 * 20];
  __shared__ float Bs[16 * 68];
  const int tid = threadIdx.x, tx = tid & 15, ty = tid >> 4;
  const int m0 = blockIdx.y * 64, n0 = blockIdx.x * 64;
  const int ar = tid >> 2, ac = (tid & 3) * 4;
  const int br = tid >> 4, bc = (tid & 15) * 4;

  float acc[4][4];
#pragma unroll
  for (int i = 0; i < 4; ++i)
#pragma unroll
    for (int j = 0; j < 4; ++j) acc[i][j] = 0.f;

  for (int kb = 0; kb < K; kb += 16){
    __syncthreads();
    *(f32x4*)&As[ar * 20 + ac] = *(const f32x4*)&A[(size_t)(m0 + ar) * K + kb + ac];
    *(f32x4*)&Bs[br * 68 + bc] = *(const f32x4*)&B[(size_t)(kb + br) * N + n0 + bc];
    __syncthreads();
#pragma unroll
    for (int kk = 0; kk < 16; ++kk){
      const f32x4 bv = *(const f32x4*)&Bs[kk * 68 + tx * 4];
#pragma unroll
      for (int i = 0; i < 4; ++i){
        const float av = As[(ty * 4 + i) * 20 + kk];
#pragma unroll
        for (int j = 0; j < 4; ++j) acc[i][j] += av * bv[j];
      }
    }
  }

#pragma unroll
  for (int i = 0; i < 4; ++i)
#pragma unroll
    for (int j = 0; j < 4; ++j){
      const int m = m0 + ty * 4 + i, n = n0 + tx * 4 + j;
      if (n < DM_) Cq[(size_t)m * DM_ + n] = acc[i][j];
      else         Ckv[(size_t)m * KV_ + (n - DM_)] = acc[i][j];
    }
}

// ---------------------------------------------------------------------------
// Naive f32 proj GEMM: out(f32) = Y(4096x2048 f32) @ W(2048x2048 f32).
// ---------------------------------------------------------------------------
__global__ __launch_bounds__(256) void proj_gemm_naive(
    const float* __restrict__ A, const float* __restrict__ B,
    float* __restrict__ C, int M, int N, int K){
  __shared__ float As[64 * 20];
  __shared__ float Bs[16 * 68];
  const int tid = threadIdx.x, tx = tid & 15, ty = tid >> 4;
  const int m0 = blockIdx.y * 64, n0 = blockIdx.x * 64;
  const int ar = tid >> 2, ac = (tid & 3) * 4;
  const int br = tid >> 4, bc = (tid & 15) * 4;

  float acc[4][4];
#pragma unroll
  for (int i = 0; i < 4; ++i)
#pragma unroll
    for (int j = 0; j < 4; ++j) acc[i][j] = 0.f;

  for (int kb = 0; kb < K; kb += 16){
    __syncthreads();
    *(f32x4*)&As[ar * 20 + ac] = *(const f32x4*)&A[(size_t)(m0 + ar) * K + kb + ac];
    *(f32x4*)&Bs[br * 68 + bc] = *(const f32x4*)&B[(size_t)(kb + br) * N + n0 + bc];
    __syncthreads();
#pragma unroll
    for (int kk = 0; kk < 16; ++kk){
      const f32x4 bv = *(const f32x4*)&Bs[kk * 68 + tx * 4];
#pragma unroll
      for (int i = 0; i < 4; ++i){
        const float av = As[(ty * 4 + i) * 20 + kk];
#pragma unroll
        for (int j = 0; j < 4; ++j) acc[i][j] += av * bv[j];
      }
    }
  }

#pragma unroll
  for (int i = 0; i < 4; ++i)
#pragma unroll
    for (int j = 0; j < 4; ++j){
      const int m = m0 + ty * 4 + i, n = n0 + tx * 4 + j;
      C[(size_t)m * N + n] = acc[i][j];
    }
}

// ---------------------------------------------------------------------------
// f32 RoPE in place: q (32 heads, fold 1/8 scale) and k (8 groups).
// One block per row (b*T+t); 1280 pairs, 5 per thread.
// ---------------------------------------------------------------------------
__global__ __launch_bounds__(256) void rope_qk_f32(
    float* __restrict__ qm, float* __restrict__ kvm){
  const int row = blockIdx.x;
  const int t = row & (T_ - 1);
#pragma unroll
  for (int it = 0; it < 5; ++it){
    const int p = threadIdx.x + it * 256;
    const int i = p & 31;
    float sv, cv;
    sincosf((float)t * exp2f(-(float)i * L2T_), &sv, &cv);
    float* ptr; float scale;
    if (p < 1024){ ptr = qm + (size_t)row * DM_ + (p >> 5) * 64 + 2 * i; scale = 0.125f; }
    else { ptr = kvm + (size_t)row * KV_ + ((p - 1024) >> 5) * 64 + 2 * i; scale = 1.f; }
    const float a = ptr[0], b = ptr[1];
    ptr[0] = (a * cv - b * sv) * scale;
    ptr[1] = (a * sv + b * cv) * scale;
  }
}

// ---------------------------------------------------------------------------
// Flash-style tiled attention, f32. v3: ALL per-thread state in NAMED SCALARS
// (rule #20: v1/v2's private arrays went to scratch when the shfl-bearing
// loop didn't unroll -> 10-15 GB of phantom scratch traffic, occupancy 16%).
// Plus T14 async-stage: K/V tile kt+1 loaded into named regs before compute
// of tile kt, ds_written after the PV barrier (global latency hidden).
// LDS: Qs + Ks(->P after QK^T) + Vs, stride 68; every pattern <=2-way per
// 16-lane phase = conflict-free. 3 barriers/tile, 3 blocks/CU.
// q pre-scaled by 1/8 in RoPE; output in place over q; reversed qt order.
// ---------------------------------------------------------------------------
#define FS 68
#define DOT4(a,b) ((a)[0]*(b)[0] + (a)[1]*(b)[1] + (a)[2]*(b)[2] + (a)[3]*(b)[3])

#define SOFTMAX_ROW(S0,S1,S2,S3,M,L,OA) { \
  float mx = fmaxf(fmaxf(S0,S1), fmaxf(S2,S3)); \
  mx = fmaxf(mx, __shfl_xor(mx,1)); mx = fmaxf(mx, __shfl_xor(mx,2)); \
  mx = fmaxf(mx, __shfl_xor(mx,4)); mx = fmaxf(mx, __shfl_xor(mx,8)); \
  const float mnew = fmaxf(M, mx); \
  const float corr = __expf(M - mnew); \
  S0 = __expf(S0 - mnew); S1 = __expf(S1 - mnew); \
  S2 = __expf(S2 - mnew); S3 = __expf(S3 - mnew); \
  float rs = S0 + S1 + S2 + S3; \
  rs += __shfl_xor(rs,1); rs += __shfl_xor(rs,2); \
  rs += __shfl_xor(rs,4); rs += __shfl_xor(rs,8); \
  M = mnew; L = L * corr + rs; OA *= corr; }

__global__ __launch_bounds__(256, 3) void attn_flash_f32(
    float* __restrict__ qy, const float* __restrict__ kv){
  __shared__ float Qs[64 * FS];
  __shared__ float Ks[64 * FS];   // K tile; reused as P tile after QK^T
  __shared__ float Vs[64 * FS];
  const int tid = threadIdx.x;
  const int tx = tid & 15, ty = tid >> 4;
  const int qt = (int)gridDim.x - 1 - (int)blockIdx.x;
  const int h = blockIdx.y, b = blockIdx.z;
  const int g = h >> 2;
  const float* kbase = kv + (size_t)b * T_ * KV_ + g * 64;
  float* qbase = qy + ((size_t)b * T_ + qt * 64) * DM_ + h * 64;

  const int sr = tid >> 4;           // staging row base (0..15)
  const int sc = (tid & 15) * 4;     // staging col (0..60)

  // ---- prologue: stage Q; load K/V tile 0 into named regs, write to LDS ----
  f32x4 kr0, kr1, kr2, kr3, vr0, vr1, vr2, vr3;
  {
    const float* kp = kbase;
    kr0 = *(const f32x4*)(kp + (size_t)(sr     ) * KV_ + sc);
    kr1 = *(const f32x4*)(kp + (size_t)(sr + 16) * KV_ + sc);
    kr2 = *(const f32x4*)(kp + (size_t)(sr + 32) * KV_ + sc);
    kr3 = *(const f32x4*)(kp + (size_t)(sr + 48) * KV_ + sc);
    const float* vp = kbase + 512;
    vr0 = *(const f32x4*)(vp + (size_t)(sr     ) * KV_ + sc);
    vr1 = *(const f32x4*)(vp + (size_t)(sr + 16) * KV_ + sc);
    vr2 = *(const f32x4*)(vp + (size_t)(sr + 32) * KV_ + sc);
    vr3 = *(const f32x4*)(vp + (size_t)(sr + 48) * KV_ + sc);
  }
#pragma unroll
  for (int it = 0; it < 4; ++it)
    *(f32x4*)&Qs[(sr + 16 * it) * FS + sc] =
        *(const f32x4*)(qbase + (size_t)(sr + 16 * it) * DM_ + sc);
  *(f32x4*)&Ks[(sr     ) * FS + sc] = kr0;
  *(f32x4*)&Ks[(sr + 16) * FS + sc] = kr1;
  *(f32x4*)&Ks[(sr + 32) * FS + sc] = kr2;
  *(f32x4*)&Ks[(sr + 48) * FS + sc] = kr3;
  *(f32x4*)&Vs[(sr     ) * FS + sc] = vr0;
  *(f32x4*)&Vs[(sr + 16) * FS + sc] = vr1;
  *(f32x4*)&Vs[(sr + 32) * FS + sc] = vr2;
  *(f32x4*)&Vs[(sr + 48) * FS + sc] = vr3;
  __syncthreads();

  float m0 = -INFINITY, m1 = -INFINITY, m2 = -INFINITY, m3 = -INFINITY;
  float l0 = 0.f, l1 = 0.f, l2 = 0.f, l3 = 0.f;
  f32x4 oa0 = {0.f,0.f,0.f,0.f}, oa1 = {0.f,0.f,0.f,0.f};
  f32x4 oa2 = {0.f,0.f,0.f,0.f}, oa3 = {0.f,0.f,0.f,0.f};

  const int r0 = 4 * ty, r1 = 4 * ty + 1, r2 = 4 * ty + 2, r3 = 4 * ty + 3;

  for (int kt = 0; kt <= qt; ++kt){
    // ---- issue prefetch of tile kt+1 into named regs (waited at ds_write) --
    if (kt < qt){
      const float* kp = kbase + (size_t)(kt + 1) * 64 * KV_;
      kr0 = *(const f32x4*)(kp + (size_t)(sr     ) * KV_ + sc);
      kr1 = *(const f32x4*)(kp + (size_t)(sr + 16) * KV_ + sc);
      kr2 = *(const f32x4*)(kp + (size_t)(sr + 32) * KV_ + sc);
      kr3 = *(const f32x4*)(kp + (size_t)(sr + 48) * KV_ + sc);
      const float* vp = kp + 512;
      vr0 = *(const f32x4*)(vp + (size_t)(sr     ) * KV_ + sc);
      vr1 = *(const f32x4*)(vp + (size_t)(sr + 16) * KV_ + sc);
      vr2 = *(const f32x4*)(vp + (size_t)(sr + 32) * KV_ + sc);
      vr3 = *(const f32x4*)(vp + (size_t)(sr + 48) * KV_ + sc);
    }

    // ---- S = Q @ K^T : named accumulators s00..s33 --------------------------
    float s00=0.f,s01=0.f,s02=0.f,s03=0.f;
    float s10=0.f,s11=0.f,s12=0.f,s13=0.f;
    float s20=0.f,s21=0.f,s22=0.f,s23=0.f;
    float s30=0.f,s31=0.f,s32=0.f,s33=0.f;
#pragma unroll
    for (int c = 0; c < 16; ++c){
      const f32x4 k0 = *(const f32x4*)&Ks[(tx     ) * FS + c * 4];
      const f32x4 k1 = *(const f32x4*)&Ks[(tx + 16) * FS + c * 4];
      const f32x4 k2 = *(const f32x4*)&Ks[(tx + 32) * FS + c * 4];
      const f32x4 k3 = *(const f32x4*)&Ks[(tx + 48) * FS + c * 4];
      const f32x4 q0 = *(const f32x4*)&Qs[r0 * FS + c * 4];
      const f32x4 q1 = *(const f32x4*)&Qs[r1 * FS + c * 4];
      const f32x4 q2 = *(const f32x4*)&Qs[r2 * FS + c * 4];
      const f32x4 q3 = *(const f32x4*)&Qs[r3 * FS + c * 4];
      s00 += DOT4(q0,k0); s01 += DOT4(q0,k1); s02 += DOT4(q0,k2); s03 += DOT4(q0,k3);
      s10 += DOT4(q1,k0); s11 += DOT4(q1,k1); s12 += DOT4(q1,k2); s13 += DOT4(q1,k3);
      s20 += DOT4(q2,k0); s21 += DOT4(q2,k1); s22 += DOT4(q2,k2); s23 += DOT4(q2,k3);
      s30 += DOT4(q3,k0); s31 += DOT4(q3,k1); s32 += DOT4(q3,k2); s33 += DOT4(q3,k3);
    }

    // ---- causal mask (diagonal tile only) ----------------------------------
    if (kt == qt){
      if (tx      > r0) s00 = -1e30f;
      if (tx + 16 > r0) s01 = -1e30f;
      if (tx + 32 > r0) s02 = -1e30f;
      if (tx + 48 > r0) s03 = -1e30f;
      if (tx      > r1) s10 = -1e30f;
      if (tx + 16 > r1) s11 = -1e30f;
      if (tx + 32 > r1) s12 = -1e30f;
      if (tx + 48 > r1) s13 = -1e30f;
      if (tx      > r2) s20 = -1e30f;
      if (tx + 16 > r2) s21 = -1e30f;
      if (tx + 32 > r2) s22 = -1e30f;
      if (tx + 48 > r2) s23 = -1e30f;
      if (tx      > r3) s30 = -1e30f;
      if (tx + 16 > r3) s31 = -1e30f;
      if (tx + 32 > r3) s32 = -1e30f;
      if (tx + 48 > r3) s33 = -1e30f;
    }

    // ---- online softmax, all named state -----------------------------------
    SOFTMAX_ROW(s00, s01, s02, s03, m0, l0, oa0);
    SOFTMAX_ROW(s10, s11, s12, s13, m1, l1, oa1);
    SOFTMAX_ROW(s20, s21, s22, s23, m2, l2, oa2);
    SOFTMAX_ROW(s30, s31, s32, s33, m3, l3, oa3);

    __syncthreads();   // all waves done reading Ks as K -> reuse as P

    Ks[r0 * FS + tx] = s00; Ks[r0 * FS + 16 + tx] = s01;
    Ks[r0 * FS + 32 + tx] = s02; Ks[r0 * FS + 48 + tx] = s03;
    Ks[r1 * FS + tx] = s10; Ks[r1 * FS + 16 + tx] = s11;
    Ks[r1 * FS + 32 + tx] = s12; Ks[r1 * FS + 48 + tx] = s13;
    Ks[r2 * FS + tx] = s20; Ks[r2 * FS + 16 + tx] = s21;
    Ks[r2 * FS + 32 + tx] = s22; Ks[r2 * FS + 48 + tx] = s23;
    Ks[r3 * FS + tx] = s30; Ks[r3 * FS + 16 + tx] = s31;
    Ks[r3 * FS + 32 + tx] = s32; Ks[r3 * FS + 48 + tx] = s33;

    // ---- O += P @ V (same-wave P rows; DS in-order per wave, no barrier) ---
#pragma unroll
    for (int kkb = 0; kkb < 16; ++kkb){
      const f32x4 p0 = *(const f32x4*)&Ks[r0 * FS + kkb * 4];
      const f32x4 p1 = *(const f32x4*)&Ks[r1 * FS + kkb * 4];
      const f32x4 p2 = *(const f32x4*)&Ks[r2 * FS + kkb * 4];
      const f32x4 p3 = *(const f32x4*)&Ks[r3 * FS + kkb * 4];
      const f32x4 v0 = *(const f32x4*)&Vs[(kkb * 4    ) * FS + tx * 4];
      const f32x4 v1 = *(const f32x4*)&Vs[(kkb * 4 + 1) * FS + tx * 4];
      const f32x4 v2 = *(const f32x4*)&Vs[(kkb * 4 + 2) * FS + tx * 4];
      const f32x4 v3 = *(const f32x4*)&Vs[(kkb * 4 + 3) * FS + tx * 4];
      oa0 += p0[0]*v0 + p0[1]*v1 + p0[2]*v2 + p0[3]*v3;
      oa1 += p1[0]*v0 + p1[1]*v1 + p1[2]*v2 + p1[3]*v3;
      oa2 += p2[0]*v0 + p2[1]*v1 + p2[2]*v2 + p2[3]*v3;
      oa3 += p3[0]*v0 + p3[1]*v1 + p3[2]*v2 + p3[3]*v3;
    }

    __syncthreads();   // all waves done with P (Ks) and Vs

    if (kt < qt){      // commit prefetched tile kt+1 (vmcnt waited here)
      *(f32x4*)&Ks[(sr     ) * FS + sc] = kr0;
      *(f32x4*)&Ks[(sr + 16) * FS + sc] = kr1;
      *(f32x4*)&Ks[(sr + 32) * FS + sc] = kr2;
      *(f32x4*)&Ks[(sr + 48) * FS + sc] = kr3;
      *(f32x4*)&Vs[(sr     ) * FS + sc] = vr0;
      *(f32x4*)&Vs[(sr + 16) * FS + sc] = vr1;
      *(f32x4*)&Vs[(sr + 32) * FS + sc] = vr2;
      *(f32x4*)&Vs[(sr + 48) * FS + sc] = vr3;
    }
    __syncthreads();   // staged writes visible to all waves
  }

  // ---- epilogue ------------------------------------------------------------
  *(f32x4*)(qbase + (size_t)r0 * DM_ + tx * 4) = oa0 * (1.f / l0);
  *(f32x4*)(qbase + (size_t)r1 * DM_ + tx * 4) = oa1 * (1.f / l1);
  *(f32x4*)(qbase + (size_t)r2 * DM_ + tx * 4) = oa2 * (1.f / l2);
  *(f32x4*)(qbase + (size_t)r3 * DM_ + tx * 4) = oa3 * (1.f / l3);
}

// ---------------------------------------------------------------------------
extern "C" void kernel_launch(void* const* d_in, const int* in_sizes, int n_in,
                              void* d_out, int out_size, void* d_ws, size_t ws_size,
                              hipStream_t stream) {
  // Select inputs by element count (robust to ordering).
  const float *x = nullptr, *w_qkv = nullptr, *w_proj = nullptr;
  for (int i = 0; i < n_in; ++i){
    if (in_sizes[i] == 8388608)      x      = (const float*)d_in[i];
    else if (in_sizes[i] == 6291456) w_qkv  = (const float*)d_in[i];
    else if (in_sizes[i] == 4194304) w_proj = (const float*)d_in[i];
  }
  float* out = (float*)d_out;   // reference output dtype is float32

  // ws (50.3 MB): qy f32 @0 (33.5MB) ; kv f32 @33.5MB (16.8MB)
  char* ws = (char*)d_ws;
  float* qy  = (float*)ws;
  float* kvb = (float*)(ws + (size_t)33554432);

  qkv_gemm_naive<<<dim3(48, 64), 256, 0, stream>>>(x, w_qkv, qy, kvb, 4096, 3072, 2048);
  rope_qk_f32<<<4096, 256, 0, stream>>>(qy, kvb);
  attn_flash_f32<<<dim3(32, 32, 2), 256, 0, stream>>>(qy, kvb);
  proj_gemm_naive<<<dim3(32, 64), 256, 0, stream>>>(qy, w_proj, out, 4096, 2048, 2048);
}

// Round 4
// 7411.293 us; speedup vs baseline: 1.9323x; 1.9323x over previous
//
#include <hip/hip_runtime.h>
#include <math.h>

typedef float f32x4 __attribute__((ext_vector_type(4)));

#define T_    2048
#define DM_   2048
#define KV_   1024
#define L2T_  0.4152410118609203f     // log2(10000)/32

// ---------------------------------------------------------------------------
// Naive f32 QKV GEMM: C = A(4096x2048) @ B(2048x3072). cols<2048 -> qy (f32,
// stride 2048), cols>=2048 -> kv (f32, stride 1024). 64x64 tile, 4x4/thread.
// ---------------------------------------------------------------------------
__global__ __launch_bounds__(256) void qkv_gemm_naive(
    const float* __restrict__ A, const float* __restrict__ B,
    float* __restrict__ Cq, float* __restrict__ Ckv, int M, int N, int K){
  __shared__ float As[64 * 20];
  __shared__ float Bs[16 * 68];
  const int tid = threadIdx.x, tx = tid & 15, ty = tid >> 4;
  const int m0 = blockIdx.y * 64, n0 = blockIdx.x * 64;
  const int ar = tid >> 2, ac = (tid & 3) * 4;
  const int br = tid >> 4, bc = (tid & 15) * 4;

  float acc[4][4];
#pragma unroll
  for (int i = 0; i < 4; ++i)
#pragma unroll
    for (int j = 0; j < 4; ++j) acc[i][j] = 0.f;

  for (int kb = 0; kb < K; kb += 16){
    __syncthreads();
    *(f32x4*)&As[ar * 20 + ac] = *(const f32x4*)&A[(size_t)(m0 + ar) * K + kb + ac];
    *(f32x4*)&Bs[br * 68 + bc] = *(const f32x4*)&B[(size_t)(kb + br) * N + n0 + bc];
    __syncthreads();
#pragma unroll
    for (int kk = 0; kk < 16; ++kk){
      const f32x4 bv = *(const f32x4*)&Bs[kk * 68 + tx * 4];
#pragma unroll
      for (int i = 0; i < 4; ++i){
        const float av = As[(ty * 4 + i) * 20 + kk];
#pragma unroll
        for (int j = 0; j < 4; ++j) acc[i][j] += av * bv[j];
      }
    }
  }

#pragma unroll
  for (int i = 0; i < 4; ++i)
#pragma unroll
    for (int j = 0; j < 4; ++j){
      const int m = m0 + ty * 4 + i, n = n0 + tx * 4 + j;
      if (n < DM_) Cq[(size_t)m * DM_ + n] = acc[i][j];
      else         Ckv[(size_t)m * KV_ + (n - DM_)] = acc[i][j];
    }
}

// ---------------------------------------------------------------------------
// Naive f32 proj GEMM: out(f32) = Y(4096x2048 f32) @ W(2048x2048 f32).
// ---------------------------------------------------------------------------
__global__ __launch_bounds__(256) void proj_gemm_naive(
    const float* __restrict__ A, const float* __restrict__ B,
    float* __restrict__ C, int M, int N, int K){
  __shared__ float As[64 * 20];
  __shared__ float Bs[16 * 68];
  const int tid = threadIdx.x, tx = tid & 15, ty = tid >> 4;
  const int m0 = blockIdx.y * 64, n0 = blockIdx.x * 64;
  const int ar = tid >> 2, ac = (tid & 3) * 4;
  const int br = tid >> 4, bc = (tid & 15) * 4;

  float acc[4][4];
#pragma unroll
  for (int i = 0; i < 4; ++i)
#pragma unroll
    for (int j = 0; j < 4; ++j) acc[i][j] = 0.f;

  for (int kb = 0; kb < K; kb += 16){
    __syncthreads();
    *(f32x4*)&As[ar * 20 + ac] = *(const f32x4*)&A[(size_t)(m0 + ar) * K + kb + ac];
    *(f32x4*)&Bs[br * 68 + bc] = *(const f32x4*)&B[(size_t)(kb + br) * N + n0 + bc];
    __syncthreads();
#pragma unroll
    for (int kk = 0; kk < 16; ++kk){
      const f32x4 bv = *(const f32x4*)&Bs[kk * 68 + tx * 4];
#pragma unroll
      for (int i = 0; i < 4; ++i){
        const float av = As[(ty * 4 + i) * 20 + kk];
#pragma unroll
        for (int j = 0; j < 4; ++j) acc[i][j] += av * bv[j];
      }
    }
  }

#pragma unroll
  for (int i = 0; i < 4; ++i)
#pragma unroll
    for (int j = 0; j < 4; ++j){
      const int m = m0 + ty * 4 + i, n = n0 + tx * 4 + j;
      C[(size_t)m * N + n] = acc[i][j];
    }
}

// ---------------------------------------------------------------------------
// f32 RoPE in place: q (32 heads, fold 1/8 scale) and k (8 groups).
// One block per row (b*T+t); 1280 pairs, 5 per thread.
// ---------------------------------------------------------------------------
__global__ __launch_bounds__(256) void rope_qk_f32(
    float* __restrict__ qm, float* __restrict__ kvm){
  const int row = blockIdx.x;
  const int t = row & (T_ - 1);
#pragma unroll
  for (int it = 0; it < 5; ++it){
    const int p = threadIdx.x + it * 256;
    const int i = p & 31;
    float sv, cv;
    sincosf((float)t * exp2f(-(float)i * L2T_), &sv, &cv);
    float* ptr; float scale;
    if (p < 1024){ ptr = qm + (size_t)row * DM_ + (p >> 5) * 64 + 2 * i; scale = 0.125f; }
    else { ptr = kvm + (size_t)row * KV_ + ((p - 1024) >> 5) * 64 + 2 * i; scale = 1.f; }
    const float a = ptr[0], b = ptr[1];
    ptr[0] = (a * cv - b * sv) * scale;
    ptr[1] = (a * sv + b * cv) * scale;
  }
}

// ---------------------------------------------------------------------------
// Flash-style tiled attention, f32. v4:
//   * amdgpu_waves_per_eu(3,3) pins the allocator at 3 waves/EU (168-VGPR
//     budget). v1-v3 all allocated EXACTLY 84 VGPR (= 512/6: the open range
//     [3,inf) from __launch_bounds__(256,3) let the allocator chase 6
//     waves/EU) and spilled 10-35 GB of scratch traffic to HBM.
//   * No register prefetch (v3's T14 attempt ADDED live state -> more spill,
//     2.4x slower). Direct global->LDS staging; 3 blocks/CU TLP hides it.
//   * All per-thread state in named scalars (rule #20 insurance).
// LDS: Qs + Ks(->P after QK^T) + Vs, stride 68; every pattern <=2-way
// bank aliasing (free). 3 barriers/tile. 52224 B -> 3 blocks/CU.
// q pre-scaled by 1/8 in RoPE; output in place over q; reversed qt order.
// ---------------------------------------------------------------------------
#define FS 68
#define DOT4(a,b) ((a)[0]*(b)[0] + (a)[1]*(b)[1] + (a)[2]*(b)[2] + (a)[3]*(b)[3])

#define SOFTMAX_ROW(S0,S1,S2,S3,M,L,OA) { \
  float mx = fmaxf(fmaxf(S0,S1), fmaxf(S2,S3)); \
  mx = fmaxf(mx, __shfl_xor(mx,1)); mx = fmaxf(mx, __shfl_xor(mx,2)); \
  mx = fmaxf(mx, __shfl_xor(mx,4)); mx = fmaxf(mx, __shfl_xor(mx,8)); \
  const float mnew = fmaxf(M, mx); \
  const float corr = __expf(M - mnew); \
  S0 = __expf(S0 - mnew); S1 = __expf(S1 - mnew); \
  S2 = __expf(S2 - mnew); S3 = __expf(S3 - mnew); \
  float rs = S0 + S1 + S2 + S3; \
  rs += __shfl_xor(rs,1); rs += __shfl_xor(rs,2); \
  rs += __shfl_xor(rs,4); rs += __shfl_xor(rs,8); \
  M = mnew; L = L * corr + rs; OA *= corr; }

__global__ __launch_bounds__(256)
__attribute__((amdgpu_waves_per_eu(3, 3)))
void attn_flash_f32(float* __restrict__ qy, const float* __restrict__ kv){
  __shared__ float Qs[64 * FS];
  __shared__ float Ks[64 * FS];   // K tile; reused as P tile after QK^T
  __shared__ float Vs[64 * FS];
  const int tid = threadIdx.x;
  const int tx = tid & 15, ty = tid >> 4;
  const int qt = (int)gridDim.x - 1 - (int)blockIdx.x;
  const int h = blockIdx.y, b = blockIdx.z;
  const int g = h >> 2;
  const float* kbase = kv + (size_t)b * T_ * KV_ + g * 64;
  const float* vbase = kbase + 512;
  float* qbase = qy + ((size_t)b * T_ + qt * 64) * DM_ + h * 64;

  const int sr = tid >> 4;           // staging row base (0..15)
  const int sc = (tid & 15) * 4;     // staging col (0..60)

  // stage Q tile once (coalesced); visible after first loop barrier
#pragma unroll
  for (int it = 0; it < 4; ++it)
    *(f32x4*)&Qs[(sr + 16 * it) * FS + sc] =
        *(const f32x4*)(qbase + (size_t)(sr + 16 * it) * DM_ + sc);

  float m0 = -INFINITY, m1 = -INFINITY, m2 = -INFINITY, m3 = -INFINITY;
  float l0 = 0.f, l1 = 0.f, l2 = 0.f, l3 = 0.f;
  f32x4 oa0 = {0.f,0.f,0.f,0.f}, oa1 = {0.f,0.f,0.f,0.f};
  f32x4 oa2 = {0.f,0.f,0.f,0.f}, oa3 = {0.f,0.f,0.f,0.f};

  const int r0 = 4 * ty, r1 = 4 * ty + 1, r2 = 4 * ty + 2, r3 = 4 * ty + 3;

  for (int kt = 0; kt <= qt; ++kt){
    __syncthreads();   // prev tile fully consumed (and Q staged, 1st iter)
    {
      const size_t grow = (size_t)(kt * 64 + sr) * KV_;
      *(f32x4*)&Ks[(sr     ) * FS + sc] = *(const f32x4*)(kbase + grow + sc);
      *(f32x4*)&Ks[(sr + 16) * FS + sc] = *(const f32x4*)(kbase + grow + 16 * KV_ + sc);
      *(f32x4*)&Ks[(sr + 32) * FS + sc] = *(const f32x4*)(kbase + grow + 32 * KV_ + sc);
      *(f32x4*)&Ks[(sr + 48) * FS + sc] = *(const f32x4*)(kbase + grow + 48 * KV_ + sc);
      *(f32x4*)&Vs[(sr     ) * FS + sc] = *(const f32x4*)(vbase + grow + sc);
      *(f32x4*)&Vs[(sr + 16) * FS + sc] = *(const f32x4*)(vbase + grow + 16 * KV_ + sc);
      *(f32x4*)&Vs[(sr + 32) * FS + sc] = *(const f32x4*)(vbase + grow + 32 * KV_ + sc);
      *(f32x4*)&Vs[(sr + 48) * FS + sc] = *(const f32x4*)(vbase + grow + 48 * KV_ + sc);
    }
    __syncthreads();

    // ---- S = Q @ K^T : named accumulators s00..s33 -------------------------
    float s00=0.f,s01=0.f,s02=0.f,s03=0.f;
    float s10=0.f,s11=0.f,s12=0.f,s13=0.f;
    float s20=0.f,s21=0.f,s22=0.f,s23=0.f;
    float s30=0.f,s31=0.f,s32=0.f,s33=0.f;
#pragma unroll
    for (int c = 0; c < 16; ++c){
      const f32x4 k0 = *(const f32x4*)&Ks[(tx     ) * FS + c * 4];
      const f32x4 k1 = *(const f32x4*)&Ks[(tx + 16) * FS + c * 4];
      const f32x4 k2 = *(const f32x4*)&Ks[(tx + 32) * FS + c * 4];
      const f32x4 k3 = *(const f32x4*)&Ks[(tx + 48) * FS + c * 4];
      const f32x4 q0 = *(const f32x4*)&Qs[r0 * FS + c * 4];
      const f32x4 q1 = *(const f32x4*)&Qs[r1 * FS + c * 4];
      const f32x4 q2 = *(const f32x4*)&Qs[r2 * FS + c * 4];
      const f32x4 q3 = *(const f32x4*)&Qs[r3 * FS + c * 4];
      s00 += DOT4(q0,k0); s01 += DOT4(q0,k1); s02 += DOT4(q0,k2); s03 += DOT4(q0,k3);
      s10 += DOT4(q1,k0); s11 += DOT4(q1,k1); s12 += DOT4(q1,k2); s13 += DOT4(q1,k3);
      s20 += DOT4(q2,k0); s21 += DOT4(q2,k1); s22 += DOT4(q2,k2); s23 += DOT4(q2,k3);
      s30 += DOT4(q3,k0); s31 += DOT4(q3,k1); s32 += DOT4(q3,k2); s33 += DOT4(q3,k3);
    }

    // ---- causal mask (diagonal tile only) ----------------------------------
    if (kt == qt){
      if (tx      > r0) s00 = -1e30f;
      if (tx + 16 > r0) s01 = -1e30f;
      if (tx + 32 > r0) s02 = -1e30f;
      if (tx + 48 > r0) s03 = -1e30f;
      if (tx      > r1) s10 = -1e30f;
      if (tx + 16 > r1) s11 = -1e30f;
      if (tx + 32 > r1) s12 = -1e30f;
      if (tx + 48 > r1) s13 = -1e30f;
      if (tx      > r2) s20 = -1e30f;
      if (tx + 16 > r2) s21 = -1e30f;
      if (tx + 32 > r2) s22 = -1e30f;
      if (tx + 48 > r2) s23 = -1e30f;
      if (tx      > r3) s30 = -1e30f;
      if (tx + 16 > r3) s31 = -1e30f;
      if (tx + 32 > r3) s32 = -1e30f;
      if (tx + 48 > r3) s33 = -1e30f;
    }

    // ---- online softmax, all named state -----------------------------------
    SOFTMAX_ROW(s00, s01, s02, s03, m0, l0, oa0);
    SOFTMAX_ROW(s10, s11, s12, s13, m1, l1, oa1);
    SOFTMAX_ROW(s20, s21, s22, s23, m2, l2, oa2);
    SOFTMAX_ROW(s30, s31, s32, s33, m3, l3, oa3);

    __syncthreads();   // all waves done reading Ks as K -> reuse as P

    Ks[r0 * FS + tx] = s00; Ks[r0 * FS + 16 + tx] = s01;
    Ks[r0 * FS + 32 + tx] = s02; Ks[r0 * FS + 48 + tx] = s03;
    Ks[r1 * FS + tx] = s10; Ks[r1 * FS + 16 + tx] = s11;
    Ks[r1 * FS + 32 + tx] = s12; Ks[r1 * FS + 48 + tx] = s13;
    Ks[r2 * FS + tx] = s20; Ks[r2 * FS + 16 + tx] = s21;
    Ks[r2 * FS + 32 + tx] = s22; Ks[r2 * FS + 48 + tx] = s23;
    Ks[r3 * FS + tx] = s30; Ks[r3 * FS + 16 + tx] = s31;
    Ks[r3 * FS + 32 + tx] = s32; Ks[r3 * FS + 48 + tx] = s33;

    // ---- O += P @ V (same-wave P rows; DS in-order per wave, no barrier) ---
#pragma unroll
    for (int kkb = 0; kkb < 16; ++kkb){
      const f32x4 p0 = *(const f32x4*)&Ks[r0 * FS + kkb * 4];
      const f32x4 p1 = *(const f32x4*)&Ks[r1 * FS + kkb * 4];
      const f32x4 p2 = *(const f32x4*)&Ks[r2 * FS + kkb * 4];
      const f32x4 p3 = *(const f32x4*)&Ks[r3 * FS + kkb * 4];
      const f32x4 v0 = *(const f32x4*)&Vs[(kkb * 4    ) * FS + tx * 4];
      const f32x4 v1 = *(const f32x4*)&Vs[(kkb * 4 + 1) * FS + tx * 4];
      const f32x4 v2 = *(const f32x4*)&Vs[(kkb * 4 + 2) * FS + tx * 4];
      const f32x4 v3 = *(const f32x4*)&Vs[(kkb * 4 + 3) * FS + tx * 4];
      oa0 += p0[0]*v0 + p0[1]*v1 + p0[2]*v2 + p0[3]*v3;
      oa1 += p1[0]*v0 + p1[1]*v1 + p1[2]*v2 + p1[3]*v3;
      oa2 += p2[0]*v0 + p2[1]*v1 + p2[2]*v2 + p2[3]*v3;
      oa3 += p3[0]*v0 + p3[1]*v1 + p3[2]*v2 + p3[3]*v3;
    }
  }

  // ---- epilogue ------------------------------------------------------------
  *(f32x4*)(qbase + (size_t)r0 * DM_ + tx * 4) = oa0 * (1.f / l0);
  *(f32x4*)(qbase + (size_t)r1 * DM_ + tx * 4) = oa1 * (1.f / l1);
  *(f32x4*)(qbase + (size_t)r2 * DM_ + tx * 4) = oa2 * (1.f / l2);
  *(f32x4*)(qbase + (size_t)r3 * DM_ + tx * 4) = oa3 * (1.f / l3);
}

// ---------------------------------------------------------------------------
extern "C" void kernel_launch(void* const* d_in, const int* in_sizes, int n_in,
                              void* d_out, int out_size, void* d_ws, size_t ws_size,
                              hipStream_t stream) {
  // Select inputs by element count (robust to ordering).
  const float *x = nullptr, *w_qkv = nullptr, *w_proj = nullptr;
  for (int i = 0; i < n_in; ++i){
    if (in_sizes[i] == 8388608)      x      = (const float*)d_in[i];
    else if (in_sizes[i] == 6291456) w_qkv  = (const float*)d_in[i];
    else if (in_sizes[i] == 4194304) w_proj = (const float*)d_in[i];
  }
  float* out = (float*)d_out;   // reference output dtype is float32

  // ws (50.3 MB): qy f32 @0 (33.5MB) ; kv f32 @33.5MB (16.8MB)
  char* ws = (char*)d_ws;
  float* qy  = (float*)ws;
  float* kvb = (float*)(ws + (size_t)33554432);

  qkv_gemm_naive<<<dim3(48, 64), 256, 0, stream>>>(x, w_qkv, qy, kvb, 4096, 3072, 2048);
  rope_qk_f32<<<4096, 256, 0, stream>>>(qy, kvb);
  attn_flash_f32<<<dim3(32, 32, 2), 256, 0, stream>>>(qy, kvb);
  proj_gemm_naive<<<dim3(32, 64), 256, 0, stream>>>(qy, w_proj, out, 4096, 2048, 2048);
}

// Round 5
// 2368.382 us; speedup vs baseline: 6.0467x; 3.1293x over previous
//
#include <hip/hip_runtime.h>
#include <math.h>

typedef float f32x4 __attribute__((ext_vector_type(4)));

#define T_    2048
#define DM_   2048
#define KV_   1024
#define L2T_  0.4152410118609203f     // log2(10000)/32

// ---------------------------------------------------------------------------
// Naive f32 QKV GEMM: C = A(4096x2048) @ B(2048x3072). cols<2048 -> qy (f32,
// stride 2048), cols>=2048 -> kv (f32, stride 1024). 64x64 tile, 4x4/thread.
// ---------------------------------------------------------------------------
__global__ __launch_bounds__(256) void qkv_gemm_naive(
    const float* __restrict__ A, const float* __restrict__ B,
    float* __restrict__ Cq, float* __restrict__ Ckv, int M, int N, int K){
  __shared__ float As[64 * 20];
  __shared__ float Bs[16 * 68];
  const int tid = threadIdx.x, tx = tid & 15, ty = tid >> 4;
  const int m0 = blockIdx.y * 64, n0 = blockIdx.x * 64;
  const int ar = tid >> 2, ac = (tid & 3) * 4;
  const int br = tid >> 4, bc = (tid & 15) * 4;

  float acc[4][4];
#pragma unroll
  for (int i = 0; i < 4; ++i)
#pragma unroll
    for (int j = 0; j < 4; ++j) acc[i][j] = 0.f;

  for (int kb = 0; kb < K; kb += 16){
    __syncthreads();
    *(f32x4*)&As[ar * 20 + ac] = *(const f32x4*)&A[(size_t)(m0 + ar) * K + kb + ac];
    *(f32x4*)&Bs[br * 68 + bc] = *(const f32x4*)&B[(size_t)(kb + br) * N + n0 + bc];
    __syncthreads();
#pragma unroll
    for (int kk = 0; kk < 16; ++kk){
      const f32x4 bv = *(const f32x4*)&Bs[kk * 68 + tx * 4];
#pragma unroll
      for (int i = 0; i < 4; ++i){
        const float av = As[(ty * 4 + i) * 20 + kk];
#pragma unroll
        for (int j = 0; j < 4; ++j) acc[i][j] += av * bv[j];
      }
    }
  }

#pragma unroll
  for (int i = 0; i < 4; ++i)
#pragma unroll
    for (int j = 0; j < 4; ++j){
      const int m = m0 + ty * 4 + i, n = n0 + tx * 4 + j;
      if (n < DM_) Cq[(size_t)m * DM_ + n] = acc[i][j];
      else         Ckv[(size_t)m * KV_ + (n - DM_)] = acc[i][j];
    }
}

// ---------------------------------------------------------------------------
// Naive f32 proj GEMM: out(f32) = Y(4096x2048 f32) @ W(2048x2048 f32).
// ---------------------------------------------------------------------------
__global__ __launch_bounds__(256) void proj_gemm_naive(
    const float* __restrict__ A, const float* __restrict__ B,
    float* __restrict__ C, int M, int N, int K){
  __shared__ float As[64 * 20];
  __shared__ float Bs[16 * 68];
  const int tid = threadIdx.x, tx = tid & 15, ty = tid >> 4;
  const int m0 = blockIdx.y * 64, n0 = blockIdx.x * 64;
  const int ar = tid >> 2, ac = (tid & 3) * 4;
  const int br = tid >> 4, bc = (tid & 15) * 4;

  float acc[4][4];
#pragma unroll
  for (int i = 0; i < 4; ++i)
#pragma unroll
    for (int j = 0; j < 4; ++j) acc[i][j] = 0.f;

  for (int kb = 0; kb < K; kb += 16){
    __syncthreads();
    *(f32x4*)&As[ar * 20 + ac] = *(const f32x4*)&A[(size_t)(m0 + ar) * K + kb + ac];
    *(f32x4*)&Bs[br * 68 + bc] = *(const f32x4*)&B[(size_t)(kb + br) * N + n0 + bc];
    __syncthreads();
#pragma unroll
    for (int kk = 0; kk < 16; ++kk){
      const f32x4 bv = *(const f32x4*)&Bs[kk * 68 + tx * 4];
#pragma unroll
      for (int i = 0; i < 4; ++i){
        const float av = As[(ty * 4 + i) * 20 + kk];
#pragma unroll
        for (int j = 0; j < 4; ++j) acc[i][j] += av * bv[j];
      }
    }
  }

#pragma unroll
  for (int i = 0; i < 4; ++i)
#pragma unroll
    for (int j = 0; j < 4; ++j){
      const int m = m0 + ty * 4 + i, n = n0 + tx * 4 + j;
      C[(size_t)m * N + n] = acc[i][j];
    }
}

// ---------------------------------------------------------------------------
// f32 RoPE in place: q (32 heads, fold 1/8 scale) and k (8 groups).
// One block per row (b*T+t); 1280 pairs, 5 per thread.
// ---------------------------------------------------------------------------
__global__ __launch_bounds__(256) void rope_qk_f32(
    float* __restrict__ qm, float* __restrict__ kvm){
  const int row = blockIdx.x;
  const int t = row & (T_ - 1);
#pragma unroll
  for (int it = 0; it < 5; ++it){
    const int p = threadIdx.x + it * 256;
    const int i = p & 31;
    float sv, cv;
    sincosf((float)t * exp2f(-(float)i * L2T_), &sv, &cv);
    float* ptr; float scale;
    if (p < 1024){ ptr = qm + (size_t)row * DM_ + (p >> 5) * 64 + 2 * i; scale = 0.125f; }
    else { ptr = kvm + (size_t)row * KV_ + ((p - 1024) >> 5) * 64 + 2 * i; scale = 1.f; }
    const float a = ptr[0], b = ptr[1];
    ptr[0] = (a * cv - b * sv) * scale;
    ptr[1] = (a * sv + b * cv) * scale;
  }
}

// ---------------------------------------------------------------------------
// Flash-style tiled attention, f32. v5: PRESSURE REDUCTION.
// v1-v4 evidence: allocator pins 84 VGPR regardless of attributes; any live
// state above that spills -> GBs of scratch HBM traffic (traffic scaled with
// state: v3 35GB > v4 18GB > v2 15GB; v0-naive @48 regs had none).
// Fix: 512 threads/block, 2 q-rows per thread (was 4). Loop-carried state
// ~15 regs, peak ~55 -- fits ANY plausible budget. unroll-4 inner loops
// bound the scheduler's live-range window.
// LDS: Qs + Ks(->P after QK^T) + Vs, stride 68; every 16-lane phase <=2-way
// or broadcast = free. 3 barriers/tile. 52224 B -> 3 blocks/CU = 24 waves.
// q pre-scaled by 1/8 in RoPE; output in place over q; reversed qt order.
// Wave w owns rows 8w..8w+7: P write + PV read stay same-wave (DS in-order).
// ---------------------------------------------------------------------------
#define FS 68
#define DOT4(a,b) ((a)[0]*(b)[0] + (a)[1]*(b)[1] + (a)[2]*(b)[2] + (a)[3]*(b)[3])

#define SOFTMAX_ROW(S0,S1,S2,S3,M,L,OA) { \
  float mx = fmaxf(fmaxf(S0,S1), fmaxf(S2,S3)); \
  mx = fmaxf(mx, __shfl_xor(mx,1)); mx = fmaxf(mx, __shfl_xor(mx,2)); \
  mx = fmaxf(mx, __shfl_xor(mx,4)); mx = fmaxf(mx, __shfl_xor(mx,8)); \
  const float mnew = fmaxf(M, mx); \
  const float corr = __expf(M - mnew); \
  S0 = __expf(S0 - mnew); S1 = __expf(S1 - mnew); \
  S2 = __expf(S2 - mnew); S3 = __expf(S3 - mnew); \
  float rs = S0 + S1 + S2 + S3; \
  rs += __shfl_xor(rs,1); rs += __shfl_xor(rs,2); \
  rs += __shfl_xor(rs,4); rs += __shfl_xor(rs,8); \
  M = mnew; L = L * corr + rs; OA *= corr; }

__global__ __launch_bounds__(512)
void attn_flash_f32(float* __restrict__ qy, const float* __restrict__ kv){
  __shared__ float Qs[64 * FS];
  __shared__ float Ks[64 * FS];   // K tile; reused as P tile after QK^T
  __shared__ float Vs[64 * FS];
  const int tid = threadIdx.x;
  const int tx = tid & 15, ty = tid >> 4;          // ty in [0,32)
  const int qt = (int)gridDim.x - 1 - (int)blockIdx.x;
  const int h = blockIdx.y, b = blockIdx.z;
  const int g = h >> 2;
  const float* kbase = kv + (size_t)b * T_ * KV_ + g * 64;
  const float* vbase = kbase + 512;
  float* qbase = qy + ((size_t)b * T_ + qt * 64) * DM_ + h * 64;

  const int sr = tid >> 4;           // staging row (0..31), second row +32
  const int sc = (tid & 15) * 4;     // staging col (0..60)

  // stage Q tile once (coalesced); visible after first loop barrier
  *(f32x4*)&Qs[(sr     ) * FS + sc] = *(const f32x4*)(qbase + (size_t)(sr     ) * DM_ + sc);
  *(f32x4*)&Qs[(sr + 32) * FS + sc] = *(const f32x4*)(qbase + (size_t)(sr + 32) * DM_ + sc);

  float m0 = -INFINITY, m1 = -INFINITY;
  float l0 = 0.f, l1 = 0.f;
  f32x4 oa0 = {0.f,0.f,0.f,0.f}, oa1 = {0.f,0.f,0.f,0.f};

  const int r0 = 2 * ty, r1 = 2 * ty + 1;

  for (int kt = 0; kt <= qt; ++kt){
    __syncthreads();   // prev tile fully consumed (and Q staged, 1st iter)
    {
      const size_t grow = (size_t)(kt * 64 + sr) * KV_;
      *(f32x4*)&Ks[(sr     ) * FS + sc] = *(const f32x4*)(kbase + grow + sc);
      *(f32x4*)&Ks[(sr + 32) * FS + sc] = *(const f32x4*)(kbase + grow + 32 * KV_ + sc);
      *(f32x4*)&Vs[(sr     ) * FS + sc] = *(const f32x4*)(vbase + grow + sc);
      *(f32x4*)&Vs[(sr + 32) * FS + sc] = *(const f32x4*)(vbase + grow + 32 * KV_ + sc);
    }
    __syncthreads();

    // ---- S = Q @ K^T : 2 rows x 4 key-groups, named accumulators -----------
    float s00=0.f,s01=0.f,s02=0.f,s03=0.f;
    float s10=0.f,s11=0.f,s12=0.f,s13=0.f;
#pragma unroll 4
    for (int c = 0; c < 16; ++c){
      const f32x4 k0 = *(const f32x4*)&Ks[(tx     ) * FS + c * 4];
      const f32x4 k1 = *(const f32x4*)&Ks[(tx + 16) * FS + c * 4];
      const f32x4 k2 = *(const f32x4*)&Ks[(tx + 32) * FS + c * 4];
      const f32x4 k3 = *(const f32x4*)&Ks[(tx + 48) * FS + c * 4];
      const f32x4 q0 = *(const f32x4*)&Qs[r0 * FS + c * 4];
      const f32x4 q1 = *(const f32x4*)&Qs[r1 * FS + c * 4];
      s00 += DOT4(q0,k0); s01 += DOT4(q0,k1); s02 += DOT4(q0,k2); s03 += DOT4(q0,k3);
      s10 += DOT4(q1,k0); s11 += DOT4(q1,k1); s12 += DOT4(q1,k2); s13 += DOT4(q1,k3);
    }

    // ---- causal mask (diagonal tile only) ----------------------------------
    if (kt == qt){
      if (tx      > r0) s00 = -1e30f;
      if (tx + 16 > r0) s01 = -1e30f;
      if (tx + 32 > r0) s02 = -1e30f;
      if (tx + 48 > r0) s03 = -1e30f;
      if (tx      > r1) s10 = -1e30f;
      if (tx + 16 > r1) s11 = -1e30f;
      if (tx + 32 > r1) s12 = -1e30f;
      if (tx + 48 > r1) s13 = -1e30f;
    }

    // ---- online softmax, all named state -----------------------------------
    SOFTMAX_ROW(s00, s01, s02, s03, m0, l0, oa0);
    SOFTMAX_ROW(s10, s11, s12, s13, m1, l1, oa1);

    __syncthreads();   // all waves done reading Ks as K -> reuse as P

    Ks[r0 * FS + tx] = s00; Ks[r0 * FS + 16 + tx] = s01;
    Ks[r0 * FS + 32 + tx] = s02; Ks[r0 * FS + 48 + tx] = s03;
    Ks[r1 * FS + tx] = s10; Ks[r1 * FS + 16 + tx] = s11;
    Ks[r1 * FS + 32 + tx] = s12; Ks[r1 * FS + 48 + tx] = s13;

    // ---- O += P @ V (same-wave P rows; DS in-order per wave, no barrier) ---
#pragma unroll 4
    for (int kkb = 0; kkb < 16; ++kkb){
      const f32x4 p0 = *(const f32x4*)&Ks[r0 * FS + kkb * 4];
      const f32x4 p1 = *(const f32x4*)&Ks[r1 * FS + kkb * 4];
      const f32x4 v0 = *(const f32x4*)&Vs[(kkb * 4    ) * FS + tx * 4];
      const f32x4 v1 = *(const f32x4*)&Vs[(kkb * 4 + 1) * FS + tx * 4];
      const f32x4 v2 = *(const f32x4*)&Vs[(kkb * 4 + 2) * FS + tx * 4];
      const f32x4 v3 = *(const f32x4*)&Vs[(kkb * 4 + 3) * FS + tx * 4];
      oa0 += p0[0]*v0 + p0[1]*v1 + p0[2]*v2 + p0[3]*v3;
      oa1 += p1[0]*v0 + p1[1]*v1 + p1[2]*v2 + p1[3]*v3;
    }
  }

  // ---- epilogue ------------------------------------------------------------
  *(f32x4*)(qbase + (size_t)r0 * DM_ + tx * 4) = oa0 * (1.f / l0);
  *(f32x4*)(qbase + (size_t)r1 * DM_ + tx * 4) = oa1 * (1.f / l1);
}

// ---------------------------------------------------------------------------
extern "C" void kernel_launch(void* const* d_in, const int* in_sizes, int n_in,
                              void* d_out, int out_size, void* d_ws, size_t ws_size,
                              hipStream_t stream) {
  // Select inputs by element count (robust to ordering).
  const float *x = nullptr, *w_qkv = nullptr, *w_proj = nullptr;
  for (int i = 0; i < n_in; ++i){
    if (in_sizes[i] == 8388608)      x      = (const float*)d_in[i];
    else if (in_sizes[i] == 6291456) w_qkv  = (const float*)d_in[i];
    else if (in_sizes[i] == 4194304) w_proj = (const float*)d_in[i];
  }
  float* out = (float*)d_out;   // reference output dtype is float32

  // ws (50.3 MB): qy f32 @0 (33.5MB) ; kv f32 @33.5MB (16.8MB)
  char* ws = (char*)d_ws;
  float* qy  = (float*)ws;
  float* kvb = (float*)(ws + (size_t)33554432);

  qkv_gemm_naive<<<dim3(48, 64), 256, 0, stream>>>(x, w_qkv, qy, kvb, 4096, 3072, 2048);
  rope_qk_f32<<<4096, 256, 0, stream>>>(qy, kvb);
  attn_flash_f32<<<dim3(32, 32, 2), 512, 0, stream>>>(qy, kvb);
  proj_gemm_naive<<<dim3(32, 64), 256, 0, stream>>>(qy, w_proj, out, 4096, 2048, 2048);
}

// Round 6
// 2324.997 us; speedup vs baseline: 6.1596x; 1.0187x over previous
//
#include <hip/hip_runtime.h>
#include <math.h>

typedef float f32x4 __attribute__((ext_vector_type(4)));

#define T_    2048
#define DM_   2048
#define KV_   1024
#define L2T_  0.4152410118609203f     // log2(10000)/32

// ---------------------------------------------------------------------------
// Naive f32 QKV GEMM: C = A(4096x2048) @ B(2048x3072). cols<2048 -> qy (f32,
// stride 2048), cols>=2048 -> kv (f32, stride 1024). 64x64 tile, 4x4/thread.
// ---------------------------------------------------------------------------
__global__ __launch_bounds__(256) void qkv_gemm_naive(
    const float* __restrict__ A, const float* __restrict__ B,
    float* __restrict__ Cq, float* __restrict__ Ckv, int M, int N, int K){
  __shared__ float As[64 * 20];
  __shared__ float Bs[16 * 68];
  const int tid = threadIdx.x, tx = tid & 15, ty = tid >> 4;
  const int m0 = blockIdx.y * 64, n0 = blockIdx.x * 64;
  const int ar = tid >> 2, ac = (tid & 3) * 4;
  const int br = tid >> 4, bc = (tid & 15) * 4;

  float acc[4][4];
#pragma unroll
  for (int i = 0; i < 4; ++i)
#pragma unroll
    for (int j = 0; j < 4; ++j) acc[i][j] = 0.f;

  for (int kb = 0; kb < K; kb += 16){
    __syncthreads();
    *(f32x4*)&As[ar * 20 + ac] = *(const f32x4*)&A[(size_t)(m0 + ar) * K + kb + ac];
    *(f32x4*)&Bs[br * 68 + bc] = *(const f32x4*)&B[(size_t)(kb + br) * N + n0 + bc];
    __syncthreads();
#pragma unroll
    for (int kk = 0; kk < 16; ++kk){
      const f32x4 bv = *(const f32x4*)&Bs[kk * 68 + tx * 4];
#pragma unroll
      for (int i = 0; i < 4; ++i){
        const float av = As[(ty * 4 + i) * 20 + kk];
#pragma unroll
        for (int j = 0; j < 4; ++j) acc[i][j] += av * bv[j];
      }
    }
  }

#pragma unroll
  for (int i = 0; i < 4; ++i)
#pragma unroll
    for (int j = 0; j < 4; ++j){
      const int m = m0 + ty * 4 + i, n = n0 + tx * 4 + j;
      if (n < DM_) Cq[(size_t)m * DM_ + n] = acc[i][j];
      else         Ckv[(size_t)m * KV_ + (n - DM_)] = acc[i][j];
    }
}

// ---------------------------------------------------------------------------
// Naive f32 proj GEMM: out(f32) = Y(4096x2048 f32) @ W(2048x2048 f32).
// ---------------------------------------------------------------------------
__global__ __launch_bounds__(256) void proj_gemm_naive(
    const float* __restrict__ A, const float* __restrict__ B,
    float* __restrict__ C, int M, int N, int K){
  __shared__ float As[64 * 20];
  __shared__ float Bs[16 * 68];
  const int tid = threadIdx.x, tx = tid & 15, ty = tid >> 4;
  const int m0 = blockIdx.y * 64, n0 = blockIdx.x * 64;
  const int ar = tid >> 2, ac = (tid & 3) * 4;
  const int br = tid >> 4, bc = (tid & 15) * 4;

  float acc[4][4];
#pragma unroll
  for (int i = 0; i < 4; ++i)
#pragma unroll
    for (int j = 0; j < 4; ++j) acc[i][j] = 0.f;

  for (int kb = 0; kb < K; kb += 16){
    __syncthreads();
    *(f32x4*)&As[ar * 20 + ac] = *(const f32x4*)&A[(size_t)(m0 + ar) * K + kb + ac];
    *(f32x4*)&Bs[br * 68 + bc] = *(const f32x4*)&B[(size_t)(kb + br) * N + n0 + bc];
    __syncthreads();
#pragma unroll
    for (int kk = 0; kk < 16; ++kk){
      const f32x4 bv = *(const f32x4*)&Bs[kk * 68 + tx * 4];
#pragma unroll
      for (int i = 0; i < 4; ++i){
        const float av = As[(ty * 4 + i) * 20 + kk];
#pragma unroll
        for (int j = 0; j < 4; ++j) acc[i][j] += av * bv[j];
      }
    }
  }

#pragma unroll
  for (int i = 0; i < 4; ++i)
#pragma unroll
    for (int j = 0; j < 4; ++j){
      const int m = m0 + ty * 4 + i, n = n0 + tx * 4 + j;
      C[(size_t)m * N + n] = acc[i][j];
    }
}

// ---------------------------------------------------------------------------
// f32 RoPE in place: q (32 heads, fold 1/8 scale) and k (8 groups).
// One block per row (b*T+t); 1280 pairs, 5 per thread.
// ---------------------------------------------------------------------------
__global__ __launch_bounds__(256) void rope_qk_f32(
    float* __restrict__ qm, float* __restrict__ kvm){
  const int row = blockIdx.x;
  const int t = row & (T_ - 1);
#pragma unroll
  for (int it = 0; it < 5; ++it){
    const int p = threadIdx.x + it * 256;
    const int i = p & 31;
    float sv, cv;
    sincosf((float)t * exp2f(-(float)i * L2T_), &sv, &cv);
    float* ptr; float scale;
    if (p < 1024){ ptr = qm + (size_t)row * DM_ + (p >> 5) * 64 + 2 * i; scale = 0.125f; }
    else { ptr = kvm + (size_t)row * KV_ + ((p - 1024) >> 5) * 64 + 2 * i; scale = 1.f; }
    const float a = ptr[0], b = ptr[1];
    ptr[0] = (a * cv - b * sv) * scale;
    ptr[1] = (a * sv + b * cv) * scale;
  }
}

// ---------------------------------------------------------------------------
// Flash-style tiled attention, f32. v6 = v5 + T14 prefetch.
// v5 fixed the spill wall (512 thr, 2 q-rows/thread, named scalars; VGPR=64,
// phantom traffic gone, attn 6500->1300us). Remaining stall: VALUBusy 39%,
// HBM 1% -- per-tile serial {global K/V load -> barrier -> compute} exposes
// L2/L3 latency. v6 issues tile kt+1's loads into 4 named f32x4 regs right
// after tile kt becomes visible; the vmcnt wait lands at the NEXT iteration's
// ds_write, so latency hides under QK+softmax+PV. +16 VGPR -> ~80, still
// under the 84 allocator wall (v3 failed this idea at 256thr/4rows: 130+
// regs -> spill. Pressure, not mechanism, was the failure).
// LDS: Qs + Ks(->P after QK^T) + Vs, stride 68; all patterns <=2-way or
// broadcast = free. 3 barriers/tile. 52224 B -> 3 blocks/CU.
// q pre-scaled by 1/8 in RoPE; output in place over q; reversed qt order.
// Wave w owns rows 8w..8w+7: P write + PV read stay same-wave (DS in-order).
// ---------------------------------------------------------------------------
#define FS 68
#define DOT4(a,b) ((a)[0]*(b)[0] + (a)[1]*(b)[1] + (a)[2]*(b)[2] + (a)[3]*(b)[3])

#define SOFTMAX_ROW(S0,S1,S2,S3,M,L,OA) { \
  float mx = fmaxf(fmaxf(S0,S1), fmaxf(S2,S3)); \
  mx = fmaxf(mx, __shfl_xor(mx,1)); mx = fmaxf(mx, __shfl_xor(mx,2)); \
  mx = fmaxf(mx, __shfl_xor(mx,4)); mx = fmaxf(mx, __shfl_xor(mx,8)); \
  const float mnew = fmaxf(M, mx); \
  const float corr = __expf(M - mnew); \
  S0 = __expf(S0 - mnew); S1 = __expf(S1 - mnew); \
  S2 = __expf(S2 - mnew); S3 = __expf(S3 - mnew); \
  float rs = S0 + S1 + S2 + S3; \
  rs += __shfl_xor(rs,1); rs += __shfl_xor(rs,2); \
  rs += __shfl_xor(rs,4); rs += __shfl_xor(rs,8); \
  M = mnew; L = L * corr + rs; OA *= corr; }

__global__ __launch_bounds__(512)
void attn_flash_f32(float* __restrict__ qy, const float* __restrict__ kv){
  __shared__ float Qs[64 * FS];
  __shared__ float Ks[64 * FS];   // K tile; reused as P tile after QK^T
  __shared__ float Vs[64 * FS];
  const int tid = threadIdx.x;
  const int tx = tid & 15, ty = tid >> 4;          // ty in [0,32)
  const int qt = (int)gridDim.x - 1 - (int)blockIdx.x;
  const int h = blockIdx.y, b = blockIdx.z;
  const int g = h >> 2;
  const float* kbase = kv + (size_t)b * T_ * KV_ + g * 64;
  const float* vbase = kbase + 512;
  float* qbase = qy + ((size_t)b * T_ + qt * 64) * DM_ + h * 64;

  const int sr = tid >> 4;           // staging row (0..31), second row +32
  const int sc = (tid & 15) * 4;     // staging col (0..60)

  // stage Q tile once (coalesced); visible after first in-loop barrier
  *(f32x4*)&Qs[(sr     ) * FS + sc] = *(const f32x4*)(qbase + (size_t)(sr     ) * DM_ + sc);
  *(f32x4*)&Qs[(sr + 32) * FS + sc] = *(const f32x4*)(qbase + (size_t)(sr + 32) * DM_ + sc);

  // prologue: load K/V tile 0 into named regs (T14 issue-early)
  f32x4 kr0, kr1, vr0, vr1;
  {
    const size_t grow = (size_t)sr * KV_;
    kr0 = *(const f32x4*)(kbase + grow + sc);
    kr1 = *(const f32x4*)(kbase + grow + 32 * KV_ + sc);
    vr0 = *(const f32x4*)(vbase + grow + sc);
    vr1 = *(const f32x4*)(vbase + grow + 32 * KV_ + sc);
  }

  float m0 = -INFINITY, m1 = -INFINITY;
  float l0 = 0.f, l1 = 0.f;
  f32x4 oa0 = {0.f,0.f,0.f,0.f}, oa1 = {0.f,0.f,0.f,0.f};

  const int r0 = 2 * ty, r1 = 2 * ty + 1;

  for (int kt = 0; kt <= qt; ++kt){
    // commit staged regs to LDS (vmcnt wait lands here; hidden under prev
    // tile's compute for kt>0). Previous tile fully consumed (end barrier).
    *(f32x4*)&Ks[(sr     ) * FS + sc] = kr0;
    *(f32x4*)&Ks[(sr + 32) * FS + sc] = kr1;
    *(f32x4*)&Vs[(sr     ) * FS + sc] = vr0;
    *(f32x4*)&Vs[(sr + 32) * FS + sc] = vr1;
    __syncthreads();   // tile kt (and Q, first iter) visible to all waves

    // issue global loads for tile kt+1 (latency hides under compute below)
    if (kt < qt){
      const size_t grow = (size_t)((kt + 1) * 64 + sr) * KV_;
      kr0 = *(const f32x4*)(kbase + grow + sc);
      kr1 = *(const f32x4*)(kbase + grow + 32 * KV_ + sc);
      vr0 = *(const f32x4*)(vbase + grow + sc);
      vr1 = *(const f32x4*)(vbase + grow + 32 * KV_ + sc);
    }

    // ---- S = Q @ K^T : 2 rows x 4 key-groups, named accumulators -----------
    float s00=0.f,s01=0.f,s02=0.f,s03=0.f;
    float s10=0.f,s11=0.f,s12=0.f,s13=0.f;
#pragma unroll 4
    for (int c = 0; c < 16; ++c){
      const f32x4 k0 = *(const f32x4*)&Ks[(tx     ) * FS + c * 4];
      const f32x4 k1 = *(const f32x4*)&Ks[(tx + 16) * FS + c * 4];
      const f32x4 k2 = *(const f32x4*)&Ks[(tx + 32) * FS + c * 4];
      const f32x4 k3 = *(const f32x4*)&Ks[(tx + 48) * FS + c * 4];
      const f32x4 q0 = *(const f32x4*)&Qs[r0 * FS + c * 4];
      const f32x4 q1 = *(const f32x4*)&Qs[r1 * FS + c * 4];
      s00 += DOT4(q0,k0); s01 += DOT4(q0,k1); s02 += DOT4(q0,k2); s03 += DOT4(q0,k3);
      s10 += DOT4(q1,k0); s11 += DOT4(q1,k1); s12 += DOT4(q1,k2); s13 += DOT4(q1,k3);
    }

    // ---- causal mask (diagonal tile only) ----------------------------------
    if (kt == qt){
      if (tx      > r0) s00 = -1e30f;
      if (tx + 16 > r0) s01 = -1e30f;
      if (tx + 32 > r0) s02 = -1e30f;
      if (tx + 48 > r0) s03 = -1e30f;
      if (tx      > r1) s10 = -1e30f;
      if (tx + 16 > r1) s11 = -1e30f;
      if (tx + 32 > r1) s12 = -1e30f;
      if (tx + 48 > r1) s13 = -1e30f;
    }

    // ---- online softmax, all named state -----------------------------------
    SOFTMAX_ROW(s00, s01, s02, s03, m0, l0, oa0);
    SOFTMAX_ROW(s10, s11, s12, s13, m1, l1, oa1);

    __syncthreads();   // all waves done reading Ks as K -> reuse as P

    Ks[r0 * FS + tx] = s00; Ks[r0 * FS + 16 + tx] = s01;
    Ks[r0 * FS + 32 + tx] = s02; Ks[r0 * FS + 48 + tx] = s03;
    Ks[r1 * FS + tx] = s10; Ks[r1 * FS + 16 + tx] = s11;
    Ks[r1 * FS + 32 + tx] = s12; Ks[r1 * FS + 48 + tx] = s13;

    // ---- O += P @ V (same-wave P rows; DS in-order per wave, no barrier) ---
#pragma unroll 4
    for (int kkb = 0; kkb < 16; ++kkb){
      const f32x4 p0 = *(const f32x4*)&Ks[r0 * FS + kkb * 4];
      const f32x4 p1 = *(const f32x4*)&Ks[r1 * FS + kkb * 4];
      const f32x4 v0 = *(const f32x4*)&Vs[(kkb * 4    ) * FS + tx * 4];
      const f32x4 v1 = *(const f32x4*)&Vs[(kkb * 4 + 1) * FS + tx * 4];
      const f32x4 v2 = *(const f32x4*)&Vs[(kkb * 4 + 2) * FS + tx * 4];
      const f32x4 v3 = *(const f32x4*)&Vs[(kkb * 4 + 3) * FS + tx * 4];
      oa0 += p0[0]*v0 + p0[1]*v1 + p0[2]*v2 + p0[3]*v3;
      oa1 += p1[0]*v0 + p1[1]*v1 + p1[2]*v2 + p1[3]*v3;
    }

    __syncthreads();   // all waves done with P(Ks)/Vs -> safe to overwrite
  }

  // ---- epilogue ------------------------------------------------------------
  *(f32x4*)(qbase + (size_t)r0 * DM_ + tx * 4) = oa0 * (1.f / l0);
  *(f32x4*)(qbase + (size_t)r1 * DM_ + tx * 4) = oa1 * (1.f / l1);
}

// ---------------------------------------------------------------------------
extern "C" void kernel_launch(void* const* d_in, const int* in_sizes, int n_in,
                              void* d_out, int out_size, void* d_ws, size_t ws_size,
                              hipStream_t stream) {
  // Select inputs by element count (robust to ordering).
  const float *x = nullptr, *w_qkv = nullptr, *w_proj = nullptr;
  for (int i = 0; i < n_in; ++i){
    if (in_sizes[i] == 8388608)      x      = (const float*)d_in[i];
    else if (in_sizes[i] == 6291456) w_qkv  = (const float*)d_in[i];
    else if (in_sizes[i] == 4194304) w_proj = (const float*)d_in[i];
  }
  float* out = (float*)d_out;   // reference output dtype is float32

  // ws (50.3 MB): qy f32 @0 (33.5MB) ; kv f32 @33.5MB (16.8MB)
  char* ws = (char*)d_ws;
  float* qy  = (float*)ws;
  float* kvb = (float*)(ws + (size_t)33554432);

  qkv_gemm_naive<<<dim3(48, 64), 256, 0, stream>>>(x, w_qkv, qy, kvb, 4096, 3072, 2048);
  rope_qk_f32<<<4096, 256, 0, stream>>>(qy, kvb);
  attn_flash_f32<<<dim3(32, 32, 2), 512, 0, stream>>>(qy, kvb);
  proj_gemm_naive<<<dim3(32, 64), 256, 0, stream>>>(qy, w_proj, out, 4096, 2048, 2048);
}

// Round 7
// 1475.566 us; speedup vs baseline: 9.7054x; 1.5757x over previous
//
#include <hip/hip_runtime.h>
#include <math.h>

typedef float f32x4 __attribute__((ext_vector_type(4)));
typedef _Float16 half_t;
typedef half_t f16x8 __attribute__((ext_vector_type(8)));

#define T_    2048
#define DM_   2048
#define KV_   1024
#define L2T_  0.4152410118609203f     // log2(10000)/32

// ---------------------------------------------------------------------------
// fp16 MFMA GEMM: C(f32) = A(Mx K f32) @ B(K x N f32), inputs converted to
// fp16 in-register during staging (error ~5e-4 << 2^-8 tolerance; bf16 would
// NOT fit the budget). 128x128 tile, BK=32, 256 thr = 4 waves in 2x2, each
// wave 64x64 = 4x4 frags of 16x16, mfma_f32_16x16x32_f16.
//   A staged [m][k] (k-contiguous = A-frag layout); B staged TRANSPOSED
//   [n][k] (B-frag wants 8 consecutive k at fixed col). LDH=40 halves makes
//   every b128 LDS access uniform-8-per-bank = BW floor (no conflicts).
//   C/D mapping (m89/m91-verified): col = lane&15, row = (lane>>4)*4 + reg.
// Output routing: whole 128-col block is either n<DM_ -> Cq (stride DM_) or
// n>=DM_ -> Ckv (stride KV_, col-DM_). For proj pass Ckv=Cq (never taken).
// ---------------------------------------------------------------------------
#define LDH 40

__global__ __launch_bounds__(256) void gemm_f16_mfma(
    const float* __restrict__ A, const float* __restrict__ B,
    float* __restrict__ Cq, float* __restrict__ Ckv, int N, int K){
  __shared__ half_t Ah[128 * LDH];
  __shared__ half_t Bh[128 * LDH];
  const int tid = threadIdx.x;
  const int m0 = blockIdx.y * 128, n0 = blockIdx.x * 128;
  const int lane = tid & 63, wid = tid >> 6;
  const int wr = wid >> 1, wc = wid & 1;     // 2x2 wave grid, 64x64 each
  const int fr = lane & 15, fg = lane >> 4;  // frag row/col, k-group

  const int sm  = tid >> 1;                  // staging row (A) / col (B): 0..127
  const int skh = (tid & 1) * 16;            // k half-offset: 0 or 16

  f32x4 acc[4][4];
#pragma unroll
  for (int i = 0; i < 4; ++i)
#pragma unroll
    for (int j = 0; j < 4; ++j) acc[i][j] = (f32x4){0.f, 0.f, 0.f, 0.f};

  const float* pa = A + (size_t)(m0 + sm) * K + skh;
  const float* pb = B + (size_t)skh * N + n0 + sm;

  for (int kb = 0; kb < K; kb += 32){
    __syncthreads();
    // ---- stage A: 16 f32 (k-contig) -> 2x f16x8 --------------------------
#pragma unroll
    for (int hh = 0; hh < 2; ++hh){
      const f32x4 u = *(const f32x4*)(pa + kb + hh * 8);
      const f32x4 v = *(const f32x4*)(pa + kb + hh * 8 + 4);
      f16x8 h;
      h[0] = (half_t)u[0]; h[1] = (half_t)u[1]; h[2] = (half_t)u[2]; h[3] = (half_t)u[3];
      h[4] = (half_t)v[0]; h[5] = (half_t)v[1]; h[6] = (half_t)v[2]; h[7] = (half_t)v[3];
      *(f16x8*)&Ah[sm * LDH + skh + hh * 8] = h;
    }
    // ---- stage B transposed: 16 strided f32 (fixed n) -> 2x f16x8 --------
#pragma unroll
    for (int hh = 0; hh < 2; ++hh){
      const float* q = pb + (size_t)(kb + hh * 8) * N;
      f16x8 h;
#pragma unroll
      for (int i = 0; i < 8; ++i) h[i] = (half_t)q[(size_t)i * N];
      *(f16x8*)&Bh[sm * LDH + skh + hh * 8] = h;
    }
    __syncthreads();

    // ---- fragments + 16 MFMA --------------------------------------------
    const f16x8 bf0 = *(const f16x8*)&Bh[(wc * 64 +  0 + fr) * LDH + fg * 8];
    const f16x8 bf1 = *(const f16x8*)&Bh[(wc * 64 + 16 + fr) * LDH + fg * 8];
    const f16x8 bf2 = *(const f16x8*)&Bh[(wc * 64 + 32 + fr) * LDH + fg * 8];
    const f16x8 bf3 = *(const f16x8*)&Bh[(wc * 64 + 48 + fr) * LDH + fg * 8];
#pragma unroll
    for (int i = 0; i < 4; ++i){
      const f16x8 af = *(const f16x8*)&Ah[(wr * 64 + i * 16 + fr) * LDH + fg * 8];
      acc[i][0] = __builtin_amdgcn_mfma_f32_16x16x32_f16(af, bf0, acc[i][0], 0, 0, 0);
      acc[i][1] = __builtin_amdgcn_mfma_f32_16x16x32_f16(af, bf1, acc[i][1], 0, 0, 0);
      acc[i][2] = __builtin_amdgcn_mfma_f32_16x16x32_f16(af, bf2, acc[i][2], 0, 0, 0);
      acc[i][3] = __builtin_amdgcn_mfma_f32_16x16x32_f16(af, bf3, acc[i][3], 0, 0, 0);
    }
  }

  // ---- epilogue: C/D col = lane&15, row = (lane>>4)*4 + reg ---------------
  const bool toq = (n0 < DM_);
  float* Cb = toq ? Cq : Ckv;
  const int stride = toq ? DM_ : KV_;
  const int cbase = n0 - (toq ? 0 : DM_) + wc * 64 + fr;
#pragma unroll
  for (int i = 0; i < 4; ++i){
    const int row = m0 + wr * 64 + i * 16 + fg * 4;
#pragma unroll
    for (int j = 0; j < 4; ++j){
      const int col = cbase + j * 16;
#pragma unroll
      for (int r = 0; r < 4; ++r)
        Cb[(size_t)(row + r) * stride + col] = acc[i][j][r];
    }
  }
}

// ---------------------------------------------------------------------------
// f32 RoPE in place: q (32 heads, fold 1/8 scale) and k (8 groups).
// One block per row (b*T+t); 1280 pairs, 5 per thread.
// ---------------------------------------------------------------------------
__global__ __launch_bounds__(256) void rope_qk_f32(
    float* __restrict__ qm, float* __restrict__ kvm){
  const int row = blockIdx.x;
  const int t = row & (T_ - 1);
#pragma unroll
  for (int it = 0; it < 5; ++it){
    const int p = threadIdx.x + it * 256;
    const int i = p & 31;
    float sv, cv;
    sincosf((float)t * exp2f(-(float)i * L2T_), &sv, &cv);
    float* ptr; float scale;
    if (p < 1024){ ptr = qm + (size_t)row * DM_ + (p >> 5) * 64 + 2 * i; scale = 0.125f; }
    else { ptr = kvm + (size_t)row * KV_ + ((p - 1024) >> 5) * 64 + 2 * i; scale = 1.f; }
    const float a = ptr[0], b = ptr[1];
    ptr[0] = (a * cv - b * sv) * scale;
    ptr[1] = (a * sv + b * cv) * scale;
  }
}

// ---------------------------------------------------------------------------
// Flash-style tiled attention, f32 (v6 structure, unchanged this round).
// 512 thr, 2 q-rows/thread, named scalars (VGPR=64, no spill), T14 prefetch.
// ---------------------------------------------------------------------------
#define FS 68
#define DOT4(a,b) ((a)[0]*(b)[0] + (a)[1]*(b)[1] + (a)[2]*(b)[2] + (a)[3]*(b)[3])

#define SOFTMAX_ROW(S0,S1,S2,S3,M,L,OA) { \
  float mx = fmaxf(fmaxf(S0,S1), fmaxf(S2,S3)); \
  mx = fmaxf(mx, __shfl_xor(mx,1)); mx = fmaxf(mx, __shfl_xor(mx,2)); \
  mx = fmaxf(mx, __shfl_xor(mx,4)); mx = fmaxf(mx, __shfl_xor(mx,8)); \
  const float mnew = fmaxf(M, mx); \
  const float corr = __expf(M - mnew); \
  S0 = __expf(S0 - mnew); S1 = __expf(S1 - mnew); \
  S2 = __expf(S2 - mnew); S3 = __expf(S3 - mnew); \
  float rs = S0 + S1 + S2 + S3; \
  rs += __shfl_xor(rs,1); rs += __shfl_xor(rs,2); \
  rs += __shfl_xor(rs,4); rs += __shfl_xor(rs,8); \
  M = mnew; L = L * corr + rs; OA *= corr; }

__global__ __launch_bounds__(512)
void attn_flash_f32(float* __restrict__ qy, const float* __restrict__ kv){
  __shared__ float Qs[64 * FS];
  __shared__ float Ks[64 * FS];   // K tile; reused as P tile after QK^T
  __shared__ float Vs[64 * FS];
  const int tid = threadIdx.x;
  const int tx = tid & 15, ty = tid >> 4;          // ty in [0,32)
  const int qt = (int)gridDim.x - 1 - (int)blockIdx.x;
  const int h = blockIdx.y, b = blockIdx.z;
  const int g = h >> 2;
  const float* kbase = kv + (size_t)b * T_ * KV_ + g * 64;
  const float* vbase = kbase + 512;
  float* qbase = qy + ((size_t)b * T_ + qt * 64) * DM_ + h * 64;

  const int sr = tid >> 4;           // staging row (0..31), second row +32
  const int sc = (tid & 15) * 4;     // staging col (0..60)

  *(f32x4*)&Qs[(sr     ) * FS + sc] = *(const f32x4*)(qbase + (size_t)(sr     ) * DM_ + sc);
  *(f32x4*)&Qs[(sr + 32) * FS + sc] = *(const f32x4*)(qbase + (size_t)(sr + 32) * DM_ + sc);

  f32x4 kr0, kr1, vr0, vr1;
  {
    const size_t grow = (size_t)sr * KV_;
    kr0 = *(const f32x4*)(kbase + grow + sc);
    kr1 = *(const f32x4*)(kbase + grow + 32 * KV_ + sc);
    vr0 = *(const f32x4*)(vbase + grow + sc);
    vr1 = *(const f32x4*)(vbase + grow + 32 * KV_ + sc);
  }

  float m0 = -INFINITY, m1 = -INFINITY;
  float l0 = 0.f, l1 = 0.f;
  f32x4 oa0 = {0.f,0.f,0.f,0.f}, oa1 = {0.f,0.f,0.f,0.f};

  const int r0 = 2 * ty, r1 = 2 * ty + 1;

  for (int kt = 0; kt <= qt; ++kt){
    *(f32x4*)&Ks[(sr     ) * FS + sc] = kr0;
    *(f32x4*)&Ks[(sr + 32) * FS + sc] = kr1;
    *(f32x4*)&Vs[(sr     ) * FS + sc] = vr0;
    *(f32x4*)&Vs[(sr + 32) * FS + sc] = vr1;
    __syncthreads();

    if (kt < qt){
      const size_t grow = (size_t)((kt + 1) * 64 + sr) * KV_;
      kr0 = *(const f32x4*)(kbase + grow + sc);
      kr1 = *(const f32x4*)(kbase + grow + 32 * KV_ + sc);
      vr0 = *(const f32x4*)(vbase + grow + sc);
      vr1 = *(const f32x4*)(vbase + grow + 32 * KV_ + sc);
    }

    float s00=0.f,s01=0.f,s02=0.f,s03=0.f;
    float s10=0.f,s11=0.f,s12=0.f,s13=0.f;
#pragma unroll 4
    for (int c = 0; c < 16; ++c){
      const f32x4 k0 = *(const f32x4*)&Ks[(tx     ) * FS + c * 4];
      const f32x4 k1 = *(const f32x4*)&Ks[(tx + 16) * FS + c * 4];
      const f32x4 k2 = *(const f32x4*)&Ks[(tx + 32) * FS + c * 4];
      const f32x4 k3 = *(const f32x4*)&Ks[(tx + 48) * FS + c * 4];
      const f32x4 q0 = *(const f32x4*)&Qs[r0 * FS + c * 4];
      const f32x4 q1 = *(const f32x4*)&Qs[r1 * FS + c * 4];
      s00 += DOT4(q0,k0); s01 += DOT4(q0,k1); s02 += DOT4(q0,k2); s03 += DOT4(q0,k3);
      s10 += DOT4(q1,k0); s11 += DOT4(q1,k1); s12 += DOT4(q1,k2); s13 += DOT4(q1,k3);
    }

    if (kt == qt){
      if (tx      > r0) s00 = -1e30f;
      if (tx + 16 > r0) s01 = -1e30f;
      if (tx + 32 > r0) s02 = -1e30f;
      if (tx + 48 > r0) s03 = -1e30f;
      if (tx      > r1) s10 = -1e30f;
      if (tx + 16 > r1) s11 = -1e30f;
      if (tx + 32 > r1) s12 = -1e30f;
      if (tx + 48 > r1) s13 = -1e30f;
    }

    SOFTMAX_ROW(s00, s01, s02, s03, m0, l0, oa0);
    SOFTMAX_ROW(s10, s11, s12, s13, m1, l1, oa1);

    __syncthreads();   // all waves done reading Ks as K -> reuse as P

    Ks[r0 * FS + tx] = s00; Ks[r0 * FS + 16 + tx] = s01;
    Ks[r0 * FS + 32 + tx] = s02; Ks[r0 * FS + 48 + tx] = s03;
    Ks[r1 * FS + tx] = s10; Ks[r1 * FS + 16 + tx] = s11;
    Ks[r1 * FS + 32 + tx] = s12; Ks[r1 * FS + 48 + tx] = s13;

#pragma unroll 4
    for (int kkb = 0; kkb < 16; ++kkb){
      const f32x4 p0 = *(const f32x4*)&Ks[r0 * FS + kkb * 4];
      const f32x4 p1 = *(const f32x4*)&Ks[r1 * FS + kkb * 4];
      const f32x4 v0 = *(const f32x4*)&Vs[(kkb * 4    ) * FS + tx * 4];
      const f32x4 v1 = *(const f32x4*)&Vs[(kkb * 4 + 1) * FS + tx * 4];
      const f32x4 v2 = *(const f32x4*)&Vs[(kkb * 4 + 2) * FS + tx * 4];
      const f32x4 v3 = *(const f32x4*)&Vs[(kkb * 4 + 3) * FS + tx * 4];
      oa0 += p0[0]*v0 + p0[1]*v1 + p0[2]*v2 + p0[3]*v3;
      oa1 += p1[0]*v0 + p1[1]*v1 + p1[2]*v2 + p1[3]*v3;
    }

    __syncthreads();
  }

  *(f32x4*)(qbase + (size_t)r0 * DM_ + tx * 4) = oa0 * (1.f / l0);
  *(f32x4*)(qbase + (size_t)r1 * DM_ + tx * 4) = oa1 * (1.f / l1);
}

// ---------------------------------------------------------------------------
extern "C" void kernel_launch(void* const* d_in, const int* in_sizes, int n_in,
                              void* d_out, int out_size, void* d_ws, size_t ws_size,
                              hipStream_t stream) {
  const float *x = nullptr, *w_qkv = nullptr, *w_proj = nullptr;
  for (int i = 0; i < n_in; ++i){
    if (in_sizes[i] == 8388608)      x      = (const float*)d_in[i];
    else if (in_sizes[i] == 6291456) w_qkv  = (const float*)d_in[i];
    else if (in_sizes[i] == 4194304) w_proj = (const float*)d_in[i];
  }
  float* out = (float*)d_out;   // reference output dtype is float32

  // ws (50.3 MB): qy f32 @0 (33.5MB) ; kv f32 @33.5MB (16.8MB)
  char* ws = (char*)d_ws;
  float* qy  = (float*)ws;
  float* kvb = (float*)(ws + (size_t)33554432);

  gemm_f16_mfma<<<dim3(24, 32), 256, 0, stream>>>(x, w_qkv, qy, kvb, 3072, 2048);
  rope_qk_f32<<<4096, 256, 0, stream>>>(qy, kvb);
  attn_flash_f32<<<dim3(32, 32, 2), 512, 0, stream>>>(qy, kvb);
  gemm_f16_mfma<<<dim3(16, 32), 256, 0, stream>>>(qy, w_proj, out, out, 2048, 2048);
}

// Round 8
// 644.671 us; speedup vs baseline: 22.2144x; 2.2889x over previous
//
#include <hip/hip_runtime.h>
#include <math.h>

typedef float f32x4 __attribute__((ext_vector_type(4)));
typedef _Float16 half_t;
typedef half_t f16x8 __attribute__((ext_vector_type(8)));

#define T_    2048
#define DM_   2048
#define KV_   1024
#define L2T_  0.4152410118609203f     // log2(10000)/32

#define CVT8(H,A,B) { H[0]=(half_t)(A)[0]; H[1]=(half_t)(A)[1]; H[2]=(half_t)(A)[2]; H[3]=(half_t)(A)[3]; \
                      H[4]=(half_t)(B)[0]; H[5]=(half_t)(B)[1]; H[6]=(half_t)(B)[2]; H[7]=(half_t)(B)[3]; }

// ---------------------------------------------------------------------------
// fp16 MFMA GEMM (unchanged from v7; verified passing). C(f32) = A @ B with
// on-the-fly f32->fp16 staging. 128x128 tile, BK=32, 4 waves 2x2.
// C/D mapping (verified end-to-end): col = lane&15, row = (lane>>4)*4 + reg.
// ---------------------------------------------------------------------------
#define LDH 40

__global__ __launch_bounds__(256) void gemm_f16_mfma(
    const float* __restrict__ A, const float* __restrict__ B,
    float* __restrict__ Cq, float* __restrict__ Ckv, int N, int K){
  __shared__ half_t Ah[128 * LDH];
  __shared__ half_t Bh[128 * LDH];
  const int tid = threadIdx.x;
  const int m0 = blockIdx.y * 128, n0 = blockIdx.x * 128;
  const int lane = tid & 63, wid = tid >> 6;
  const int wr = wid >> 1, wc = wid & 1;
  const int fr = lane & 15, fg = lane >> 4;

  const int sm  = tid >> 1;
  const int skh = (tid & 1) * 16;

  f32x4 acc[4][4];
#pragma unroll
  for (int i = 0; i < 4; ++i)
#pragma unroll
    for (int j = 0; j < 4; ++j) acc[i][j] = (f32x4){0.f, 0.f, 0.f, 0.f};

  const float* pa = A + (size_t)(m0 + sm) * K + skh;
  const float* pb = B + (size_t)skh * N + n0 + sm;

  for (int kb = 0; kb < K; kb += 32){
    __syncthreads();
#pragma unroll
    for (int hh = 0; hh < 2; ++hh){
      const f32x4 u = *(const f32x4*)(pa + kb + hh * 8);
      const f32x4 v = *(const f32x4*)(pa + kb + hh * 8 + 4);
      f16x8 h; CVT8(h, u, v);
      *(f16x8*)&Ah[sm * LDH + skh + hh * 8] = h;
    }
#pragma unroll
    for (int hh = 0; hh < 2; ++hh){
      const float* q = pb + (size_t)(kb + hh * 8) * N;
      f16x8 h;
#pragma unroll
      for (int i = 0; i < 8; ++i) h[i] = (half_t)q[(size_t)i * N];
      *(f16x8*)&Bh[sm * LDH + skh + hh * 8] = h;
    }
    __syncthreads();

    const f16x8 bf0 = *(const f16x8*)&Bh[(wc * 64 +  0 + fr) * LDH + fg * 8];
    const f16x8 bf1 = *(const f16x8*)&Bh[(wc * 64 + 16 + fr) * LDH + fg * 8];
    const f16x8 bf2 = *(const f16x8*)&Bh[(wc * 64 + 32 + fr) * LDH + fg * 8];
    const f16x8 bf3 = *(const f16x8*)&Bh[(wc * 64 + 48 + fr) * LDH + fg * 8];
#pragma unroll
    for (int i = 0; i < 4; ++i){
      const f16x8 af = *(const f16x8*)&Ah[(wr * 64 + i * 16 + fr) * LDH + fg * 8];
      acc[i][0] = __builtin_amdgcn_mfma_f32_16x16x32_f16(af, bf0, acc[i][0], 0, 0, 0);
      acc[i][1] = __builtin_amdgcn_mfma_f32_16x16x32_f16(af, bf1, acc[i][1], 0, 0, 0);
      acc[i][2] = __builtin_amdgcn_mfma_f32_16x16x32_f16(af, bf2, acc[i][2], 0, 0, 0);
      acc[i][3] = __builtin_amdgcn_mfma_f32_16x16x32_f16(af, bf3, acc[i][3], 0, 0, 0);
    }
  }

  const bool toq = (n0 < DM_);
  float* Cb = toq ? Cq : Ckv;
  const int stride = toq ? DM_ : KV_;
  const int cbase = n0 - (toq ? 0 : DM_) + wc * 64 + fr;
#pragma unroll
  for (int i = 0; i < 4; ++i){
    const int row = m0 + wr * 64 + i * 16 + fg * 4;
#pragma unroll
    for (int j = 0; j < 4; ++j){
      const int col = cbase + j * 16;
#pragma unroll
      for (int r = 0; r < 4; ++r)
        Cb[(size_t)(row + r) * stride + col] = acc[i][j][r];
    }
  }
}

// ---------------------------------------------------------------------------
// f32 RoPE in place (unchanged): q (fold 1/8 scale) and k.
// ---------------------------------------------------------------------------
__global__ __launch_bounds__(256) void rope_qk_f32(
    float* __restrict__ qm, float* __restrict__ kvm){
  const int row = blockIdx.x;
  const int t = row & (T_ - 1);
#pragma unroll
  for (int it = 0; it < 5; ++it){
    const int p = threadIdx.x + it * 256;
    const int i = p & 31;
    float sv, cv;
    sincosf((float)t * exp2f(-(float)i * L2T_), &sv, &cv);
    float* ptr; float scale;
    if (p < 1024){ ptr = qm + (size_t)row * DM_ + (p >> 5) * 64 + 2 * i; scale = 0.125f; }
    else { ptr = kvm + (size_t)row * KV_ + ((p - 1024) >> 5) * 64 + 2 * i; scale = 1.f; }
    const float a = ptr[0], b = ptr[1];
    ptr[0] = (a * cv - b * sv) * scale;
    ptr[1] = (a * sv + b * cv) * scale;
  }
}

// ---------------------------------------------------------------------------
// Flash attention v8: fp16 MFMA for QK^T and PV. 256 thr / 4 waves; wave owns
// 16 q-rows of a 64-row q-tile; 64-key tiles.
//   Operand mapping (verified by the passing v7 GEMM):
//     A-frag: row=lane&15, k=8*(lane>>4)+j (contiguous 8)
//     B-frag: col=lane&15, k=8*(lane>>4)+j (contiguous 8)
//     C/D:    col=lane&15, row=4*(lane>>4)+reg
//   Q,K row-major fp16 [64][72]; V TRANSPOSED [d][key] fp16 [64][72]
//   (coalesced scalar-f32 global reads, contiguous f16x8 LDS writes).
//   S rows == C rows -> softmax state m/l/corr are f32x4 indexed by reg;
//   O-frag rescale is elementwise vector math. P round-trips via per-wave
//   LDS [cb][row][20] (u16 writes ~2-way; contiguous A-frag reads;
//   same-wave write->read, DS in-order, no barrier).
// 2 barriers/tile. LDS 37888 B -> 4 blocks/CU. All state named/static.
// ---------------------------------------------------------------------------
#define LDQ 72
#define LDV 72
#define LDP 20

#define VMAX(A,B) (f32x4){fmaxf((A)[0],(B)[0]), fmaxf((A)[1],(B)[1]), fmaxf((A)[2],(B)[2]), fmaxf((A)[3],(B)[3])}
#define MAXRED(V,S) { V[0]=fmaxf(V[0],__shfl_xor(V[0],S)); V[1]=fmaxf(V[1],__shfl_xor(V[1],S)); \
                      V[2]=fmaxf(V[2],__shfl_xor(V[2],S)); V[3]=fmaxf(V[3],__shfl_xor(V[3],S)); }
#define SUMRED(V,S) { V[0]+=__shfl_xor(V[0],S); V[1]+=__shfl_xor(V[1],S); \
                      V[2]+=__shfl_xor(V[2],S); V[3]+=__shfl_xor(V[3],S); }
#define EXP4(SV) { SV[0]=__expf(SV[0]-mnew[0]); SV[1]=__expf(SV[1]-mnew[1]); \
                   SV[2]=__expf(SV[2]-mnew[2]); SV[3]=__expf(SV[3]-mnew[3]); }
#define PSTORE(SV,CB) { Ph[pw + (CB)*320 + (pr+0)*LDP + fr] = (half_t)SV[0]; \
                        Ph[pw + (CB)*320 + (pr+1)*LDP + fr] = (half_t)SV[1]; \
                        Ph[pw + (CB)*320 + (pr+2)*LDP + fr] = (half_t)SV[2]; \
                        Ph[pw + (CB)*320 + (pr+3)*LDP + fr] = (half_t)SV[3]; }

__global__ __launch_bounds__(256) void attn_flash_mfma(
    float* __restrict__ qy, const float* __restrict__ kv){
  __shared__ half_t Qh[64 * LDQ];
  __shared__ half_t Kh[64 * LDQ];
  __shared__ half_t Vt[64 * LDV];
  __shared__ half_t Ph[4 * 4 * 16 * LDP];
  const int tid = threadIdx.x;
  const int lane = tid & 63, w = tid >> 6;
  const int fr = lane & 15, fg = lane >> 4;
  const int qt = (int)gridDim.x - 1 - (int)blockIdx.x;
  const int h = blockIdx.y, b = blockIdx.z;
  const int g = h >> 2;
  const float* kbase = kv + (size_t)b * T_ * KV_ + g * 64;
  const float* vbase = kbase + 512;
  float* qbase = qy + ((size_t)b * T_ + qt * 64) * DM_ + h * 64;

  const int srow = tid >> 2, sc0 = (tid & 3) * 16;   // Q/K staging coords
  const int vd = tid & 63, vk8 = (tid >> 6) * 8;     // V^T staging coords

  // ---- stage Q once (visible after first in-loop barrier) -----------------
  {
    const float* src = qbase + (size_t)srow * DM_ + sc0;
    const f32x4 u0 = *(const f32x4*)(src);
    const f32x4 u1 = *(const f32x4*)(src + 4);
    const f32x4 u2 = *(const f32x4*)(src + 8);
    const f32x4 u3 = *(const f32x4*)(src + 12);
    f16x8 h0, h1; CVT8(h0, u0, u1); CVT8(h1, u2, u3);
    *(f16x8*)&Qh[srow * LDQ + sc0] = h0;
    *(f16x8*)&Qh[srow * LDQ + sc0 + 8] = h1;
  }

  f32x4 m = {-INFINITY, -INFINITY, -INFINITY, -INFINITY};
  f32x4 l = {0.f, 0.f, 0.f, 0.f};
  f32x4 o0 = {0.f,0.f,0.f,0.f}, o1 = {0.f,0.f,0.f,0.f};
  f32x4 o2 = {0.f,0.f,0.f,0.f}, o3 = {0.f,0.f,0.f,0.f};

  const int arow = (w * 16 + fr) * LDQ;
  const int pw = w * (4 * 16 * LDP);
  const int pr = fg * 4;

  for (int kt = 0; kt <= qt; ++kt){
    // ---- stage K (row-major) and V (transposed) ---------------------------
    {
      const float* src = kbase + (size_t)(kt * 64 + srow) * KV_ + sc0;
      const f32x4 u0 = *(const f32x4*)(src);
      const f32x4 u1 = *(const f32x4*)(src + 4);
      const f32x4 u2 = *(const f32x4*)(src + 8);
      const f32x4 u3 = *(const f32x4*)(src + 12);
      f16x8 h0, h1; CVT8(h0, u0, u1); CVT8(h1, u2, u3);
      *(f16x8*)&Kh[srow * LDQ + sc0] = h0;
      *(f16x8*)&Kh[srow * LDQ + sc0 + 8] = h1;
    }
#pragma unroll
    for (int it = 0; it < 2; ++it){
      const int k0 = vk8 + it * 32;
      const float* src = vbase + (size_t)(kt * 64 + k0) * KV_ + vd;
      f16x8 hv;
      hv[0] = (half_t)src[0];
      hv[1] = (half_t)src[KV_];
      hv[2] = (half_t)src[2 * KV_];
      hv[3] = (half_t)src[3 * KV_];
      hv[4] = (half_t)src[4 * KV_];
      hv[5] = (half_t)src[5 * KV_];
      hv[6] = (half_t)src[6 * KV_];
      hv[7] = (half_t)src[7 * KV_];
      *(f16x8*)&Vt[vd * LDV + k0] = hv;
    }
    __syncthreads();

    // ---- S = Q @ K^T : 8 MFMA ---------------------------------------------
    const f16x8 aq0 = *(const f16x8*)&Qh[arow + fg * 8];
    const f16x8 aq1 = *(const f16x8*)&Qh[arow + 32 + fg * 8];
    f32x4 s0 = {0.f,0.f,0.f,0.f}, s1 = {0.f,0.f,0.f,0.f};
    f32x4 s2 = {0.f,0.f,0.f,0.f}, s3 = {0.f,0.f,0.f,0.f};
    {
      const f16x8 b0 = *(const f16x8*)&Kh[(fr     ) * LDQ + fg * 8];
      const f16x8 b1 = *(const f16x8*)&Kh[(fr     ) * LDQ + 32 + fg * 8];
      s0 = __builtin_amdgcn_mfma_f32_16x16x32_f16(aq0, b0, s0, 0, 0, 0);
      s0 = __builtin_amdgcn_mfma_f32_16x16x32_f16(aq1, b1, s0, 0, 0, 0);
    }
    {
      const f16x8 b0 = *(const f16x8*)&Kh[(16 + fr) * LDQ + fg * 8];
      const f16x8 b1 = *(const f16x8*)&Kh[(16 + fr) * LDQ + 32 + fg * 8];
      s1 = __builtin_amdgcn_mfma_f32_16x16x32_f16(aq0, b0, s1, 0, 0, 0);
      s1 = __builtin_amdgcn_mfma_f32_16x16x32_f16(aq1, b1, s1, 0, 0, 0);
    }
    {
      const f16x8 b0 = *(const f16x8*)&Kh[(32 + fr) * LDQ + fg * 8];
      const f16x8 b1 = *(const f16x8*)&Kh[(32 + fr) * LDQ + 32 + fg * 8];
      s2 = __builtin_amdgcn_mfma_f32_16x16x32_f16(aq0, b0, s2, 0, 0, 0);
      s2 = __builtin_amdgcn_mfma_f32_16x16x32_f16(aq1, b1, s2, 0, 0, 0);
    }
    {
      const f16x8 b0 = *(const f16x8*)&Kh[(48 + fr) * LDQ + fg * 8];
      const f16x8 b1 = *(const f16x8*)&Kh[(48 + fr) * LDQ + 32 + fg * 8];
      s3 = __builtin_amdgcn_mfma_f32_16x16x32_f16(aq0, b0, s3, 0, 0, 0);
      s3 = __builtin_amdgcn_mfma_f32_16x16x32_f16(aq1, b1, s3, 0, 0, 0);
    }

    // ---- causal mask (diagonal tile): key cb*16+fr > qrow w*16+fg*4+reg ---
    if (kt == qt){
      const int qr = w * 16 + fg * 4;
      if (fr      > qr    ) s0[0] = -1e30f;
      if (fr      > qr + 1) s0[1] = -1e30f;
      if (fr      > qr + 2) s0[2] = -1e30f;
      if (fr      > qr + 3) s0[3] = -1e30f;
      if (fr + 16 > qr    ) s1[0] = -1e30f;
      if (fr + 16 > qr + 1) s1[1] = -1e30f;
      if (fr + 16 > qr + 2) s1[2] = -1e30f;
      if (fr + 16 > qr + 3) s1[3] = -1e30f;
      if (fr + 32 > qr    ) s2[0] = -1e30f;
      if (fr + 32 > qr + 1) s2[1] = -1e30f;
      if (fr + 32 > qr + 2) s2[2] = -1e30f;
      if (fr + 32 > qr + 3) s2[3] = -1e30f;
      if (fr + 48 > qr    ) s3[0] = -1e30f;
      if (fr + 48 > qr + 1) s3[1] = -1e30f;
      if (fr + 48 > qr + 2) s3[2] = -1e30f;
      if (fr + 48 > qr + 3) s3[3] = -1e30f;
    }

    // ---- online softmax (rows = C rows; 16-lane groups share a row) -------
    f32x4 vm = VMAX(VMAX(s0, s1), VMAX(s2, s3));
    MAXRED(vm, 1); MAXRED(vm, 2); MAXRED(vm, 4); MAXRED(vm, 8);
    const f32x4 mnew = VMAX(m, vm);
    f32x4 corr;
    corr[0] = __expf(m[0] - mnew[0]);
    corr[1] = __expf(m[1] - mnew[1]);
    corr[2] = __expf(m[2] - mnew[2]);
    corr[3] = __expf(m[3] - mnew[3]);
    EXP4(s0); EXP4(s1); EXP4(s2); EXP4(s3);
    f32x4 rs = s0 + s1 + s2 + s3;
    SUMRED(rs, 1); SUMRED(rs, 2); SUMRED(rs, 4); SUMRED(rs, 8);
    m = mnew;
    l = l * corr + rs;
    o0 *= corr; o1 *= corr; o2 *= corr; o3 *= corr;

    // ---- P -> LDS (same-wave region; DS in-order; no barrier) -------------
    PSTORE(s0, 0); PSTORE(s1, 1); PSTORE(s2, 2); PSTORE(s3, 3);

    // ---- O += P @ V : 8 MFMA ----------------------------------------------
    const f16x8 pa0 = *(const f16x8*)&Ph[pw + ((fg >> 1)    ) * 320 + fr * LDP + (fg & 1) * 8];
    const f16x8 pa1 = *(const f16x8*)&Ph[pw + (2 + (fg >> 1)) * 320 + fr * LDP + (fg & 1) * 8];
    {
      const f16x8 b0 = *(const f16x8*)&Vt[(fr     ) * LDV + fg * 8];
      const f16x8 b1 = *(const f16x8*)&Vt[(fr     ) * LDV + 32 + fg * 8];
      o0 = __builtin_amdgcn_mfma_f32_16x16x32_f16(pa0, b0, o0, 0, 0, 0);
      o0 = __builtin_amdgcn_mfma_f32_16x16x32_f16(pa1, b1, o0, 0, 0, 0);
    }
    {
      const f16x8 b0 = *(const f16x8*)&Vt[(16 + fr) * LDV + fg * 8];
      const f16x8 b1 = *(const f16x8*)&Vt[(16 + fr) * LDV + 32 + fg * 8];
      o1 = __builtin_amdgcn_mfma_f32_16x16x32_f16(pa0, b0, o1, 0, 0, 0);
      o1 = __builtin_amdgcn_mfma_f32_16x16x32_f16(pa1, b1, o1, 0, 0, 0);
    }
    {
      const f16x8 b0 = *(const f16x8*)&Vt[(32 + fr) * LDV + fg * 8];
      const f16x8 b1 = *(const f16x8*)&Vt[(32 + fr) * LDV + 32 + fg * 8];
      o2 = __builtin_amdgcn_mfma_f32_16x16x32_f16(pa0, b0, o2, 0, 0, 0);
      o2 = __builtin_amdgcn_mfma_f32_16x16x32_f16(pa1, b1, o2, 0, 0, 0);
    }
    {
      const f16x8 b0 = *(const f16x8*)&Vt[(48 + fr) * LDV + fg * 8];
      const f16x8 b1 = *(const f16x8*)&Vt[(48 + fr) * LDV + 32 + fg * 8];
      o3 = __builtin_amdgcn_mfma_f32_16x16x32_f16(pa0, b0, o3, 0, 0, 0);
      o3 = __builtin_amdgcn_mfma_f32_16x16x32_f16(pa1, b1, o3, 0, 0, 0);
    }

    __syncthreads();   // all waves done with Kh/Vt -> safe to re-stage
  }

  // ---- epilogue ------------------------------------------------------------
  f32x4 inv;
  inv[0] = 1.f / l[0]; inv[1] = 1.f / l[1];
  inv[2] = 1.f / l[2]; inv[3] = 1.f / l[3];
  o0 *= inv; o1 *= inv; o2 *= inv; o3 *= inv;
  const int orow = w * 16 + fg * 4;
  float* dst = qbase + (size_t)orow * DM_ + fr;
  dst[(size_t)0 * DM_ +  0] = o0[0]; dst[(size_t)1 * DM_ +  0] = o0[1];
  dst[(size_t)2 * DM_ +  0] = o0[2]; dst[(size_t)3 * DM_ +  0] = o0[3];
  dst[(size_t)0 * DM_ + 16] = o1[0]; dst[(size_t)1 * DM_ + 16] = o1[1];
  dst[(size_t)2 * DM_ + 16] = o1[2]; dst[(size_t)3 * DM_ + 16] = o1[3];
  dst[(size_t)0 * DM_ + 32] = o2[0]; dst[(size_t)1 * DM_ + 32] = o2[1];
  dst[(size_t)2 * DM_ + 32] = o2[2]; dst[(size_t)3 * DM_ + 32] = o2[3];
  dst[(size_t)0 * DM_ + 48] = o3[0]; dst[(size_t)1 * DM_ + 48] = o3[1];
  dst[(size_t)2 * DM_ + 48] = o3[2]; dst[(size_t)3 * DM_ + 48] = o3[3];
}

// ---------------------------------------------------------------------------
extern "C" void kernel_launch(void* const* d_in, const int* in_sizes, int n_in,
                              void* d_out, int out_size, void* d_ws, size_t ws_size,
                              hipStream_t stream) {
  const float *x = nullptr, *w_qkv = nullptr, *w_proj = nullptr;
  for (int i = 0; i < n_in; ++i){
    if (in_sizes[i] == 8388608)      x      = (const float*)d_in[i];
    else if (in_sizes[i] == 6291456) w_qkv  = (const float*)d_in[i];
    else if (in_sizes[i] == 4194304) w_proj = (const float*)d_in[i];
  }
  float* out = (float*)d_out;   // reference output dtype is float32

  // ws (50.3 MB): qy f32 @0 (33.5MB) ; kv f32 @33.5MB (16.8MB)
  char* ws = (char*)d_ws;
  float* qy  = (float*)ws;
  float* kvb = (float*)(ws + (size_t)33554432);

  gemm_f16_mfma<<<dim3(24, 32), 256, 0, stream>>>(x, w_qkv, qy, kvb, 3072, 2048);
  rope_qk_f32<<<4096, 256, 0, stream>>>(qy, kvb);
  attn_flash_mfma<<<dim3(32, 32, 2), 256, 0, stream>>>(qy, kvb);
  gemm_f16_mfma<<<dim3(16, 32), 256, 0, stream>>>(qy, w_proj, out, out, 2048, 2048);
}

// Round 9
// 639.254 us; speedup vs baseline: 22.4027x; 1.0085x over previous
//
#include <hip/hip_runtime.h>
#include <math.h>

typedef float f32x4 __attribute__((ext_vector_type(4)));
typedef _Float16 half_t;
typedef half_t f16x8 __attribute__((ext_vector_type(8)));

#define T_    2048
#define DM_   2048
#define KV_   1024
#define L2T_  0.4152410118609203f     // log2(10000)/32

#define CVT8(H,A,B) { H[0]=(half_t)(A)[0]; H[1]=(half_t)(A)[1]; H[2]=(half_t)(A)[2]; H[3]=(half_t)(A)[3]; \
                      H[4]=(half_t)(B)[0]; H[5]=(half_t)(B)[1]; H[6]=(half_t)(B)[2]; H[7]=(half_t)(B)[3]; }

// ---------------------------------------------------------------------------
// fp16 MFMA GEMM (v7-verified core) + T1 bijective XCD swizzle: linearized
// block id remapped so each XCD owns a contiguous run of same-row tiles ->
// A-panel stays in that XCD's private L2 (nwg divisible by 8 for both
// launches: 768, 512). C/D mapping: col = lane&15, row = (lane>>4)*4 + reg.
// ---------------------------------------------------------------------------
#define LDH 40

__global__ __launch_bounds__(256) void gemm_f16_mfma(
    const float* __restrict__ A, const float* __restrict__ B,
    float* __restrict__ Cq, float* __restrict__ Ckv, int N, int K){
  __shared__ half_t Ah[128 * LDH];
  __shared__ half_t Bh[128 * LDH];
  const int tid = threadIdx.x;

  // XCD-aware bijective remap (nwg % 8 == 0 guaranteed by launch config)
  const int nwg = (int)(gridDim.x * gridDim.y);
  int lin = (int)blockIdx.y * (int)gridDim.x + (int)blockIdx.x;
  lin = (lin & 7) * (nwg >> 3) + (lin >> 3);
  const int m0 = (lin / (int)gridDim.x) * 128;
  const int n0 = (lin % (int)gridDim.x) * 128;

  const int lane = tid & 63, wid = tid >> 6;
  const int wr = wid >> 1, wc = wid & 1;
  const int fr = lane & 15, fg = lane >> 4;

  const int sm  = tid >> 1;
  const int skh = (tid & 1) * 16;

  f32x4 acc[4][4];
#pragma unroll
  for (int i = 0; i < 4; ++i)
#pragma unroll
    for (int j = 0; j < 4; ++j) acc[i][j] = (f32x4){0.f, 0.f, 0.f, 0.f};

  const float* pa = A + (size_t)(m0 + sm) * K + skh;
  const float* pb = B + (size_t)skh * N + n0 + sm;

  for (int kb = 0; kb < K; kb += 32){
    __syncthreads();
#pragma unroll
    for (int hh = 0; hh < 2; ++hh){
      const f32x4 u = *(const f32x4*)(pa + kb + hh * 8);
      const f32x4 v = *(const f32x4*)(pa + kb + hh * 8 + 4);
      f16x8 h; CVT8(h, u, v);
      *(f16x8*)&Ah[sm * LDH + skh + hh * 8] = h;
    }
#pragma unroll
    for (int hh = 0; hh < 2; ++hh){
      const float* q = pb + (size_t)(kb + hh * 8) * N;
      f16x8 h;
#pragma unroll
      for (int i = 0; i < 8; ++i) h[i] = (half_t)q[(size_t)i * N];
      *(f16x8*)&Bh[sm * LDH + skh + hh * 8] = h;
    }
    __syncthreads();

    const f16x8 bf0 = *(const f16x8*)&Bh[(wc * 64 +  0 + fr) * LDH + fg * 8];
    const f16x8 bf1 = *(const f16x8*)&Bh[(wc * 64 + 16 + fr) * LDH + fg * 8];
    const f16x8 bf2 = *(const f16x8*)&Bh[(wc * 64 + 32 + fr) * LDH + fg * 8];
    const f16x8 bf3 = *(const f16x8*)&Bh[(wc * 64 + 48 + fr) * LDH + fg * 8];
#pragma unroll
    for (int i = 0; i < 4; ++i){
      const f16x8 af = *(const f16x8*)&Ah[(wr * 64 + i * 16 + fr) * LDH + fg * 8];
      acc[i][0] = __builtin_amdgcn_mfma_f32_16x16x32_f16(af, bf0, acc[i][0], 0, 0, 0);
      acc[i][1] = __builtin_amdgcn_mfma_f32_16x16x32_f16(af, bf1, acc[i][1], 0, 0, 0);
      acc[i][2] = __builtin_amdgcn_mfma_f32_16x16x32_f16(af, bf2, acc[i][2], 0, 0, 0);
      acc[i][3] = __builtin_amdgcn_mfma_f32_16x16x32_f16(af, bf3, acc[i][3], 0, 0, 0);
    }
  }

  const bool toq = (n0 < DM_);
  float* Cb = toq ? Cq : Ckv;
  const int stride = toq ? DM_ : KV_;
  const int cbase = n0 - (toq ? 0 : DM_) + wc * 64 + fr;
#pragma unroll
  for (int i = 0; i < 4; ++i){
    const int row = m0 + wr * 64 + i * 16 + fg * 4;
#pragma unroll
    for (int j = 0; j < 4; ++j){
      const int col = cbase + j * 16;
#pragma unroll
      for (int r = 0; r < 4; ++r)
        Cb[(size_t)(row + r) * stride + col] = acc[i][j][r];
    }
  }
}

// ---------------------------------------------------------------------------
// f32 RoPE in place (unchanged): q (fold 1/8 scale) and k.
// ---------------------------------------------------------------------------
__global__ __launch_bounds__(256) void rope_qk_f32(
    float* __restrict__ qm, float* __restrict__ kvm){
  const int row = blockIdx.x;
  const int t = row & (T_ - 1);
#pragma unroll
  for (int it = 0; it < 5; ++it){
    const int p = threadIdx.x + it * 256;
    const int i = p & 31;
    float sv, cv;
    sincosf((float)t * exp2f(-(float)i * L2T_), &sv, &cv);
    float* ptr; float scale;
    if (p < 1024){ ptr = qm + (size_t)row * DM_ + (p >> 5) * 64 + 2 * i; scale = 0.125f; }
    else { ptr = kvm + (size_t)row * KV_ + ((p - 1024) >> 5) * 64 + 2 * i; scale = 1.f; }
    const float a = ptr[0], b = ptr[1];
    ptr[0] = (a * cv - b * sv) * scale;
    ptr[1] = (a * sv + b * cv) * scale;
  }
}

// ---------------------------------------------------------------------------
// Flash attention v9 = v8 with Q-frags hoisted to REGISTERS.
//   Q is staged once through the Kh buffer pre-loop, each wave reads its two
//   A-frags (8 VGPR) and Qh is deleted -> LDS 37888 -> 28672 B = 5 blocks/CU
//   (was ~3-4), and 2 fewer b128 reads per tile. VGPR ~75 < 84 wall (v4).
//   All per-tile logic (verified passing in v8) unchanged.
// ---------------------------------------------------------------------------
#define LDQ 72
#define LDV 72
#define LDP 20

#define VMAX(A,B) (f32x4){fmaxf((A)[0],(B)[0]), fmaxf((A)[1],(B)[1]), fmaxf((A)[2],(B)[2]), fmaxf((A)[3],(B)[3])}
#define MAXRED(V,S) { V[0]=fmaxf(V[0],__shfl_xor(V[0],S)); V[1]=fmaxf(V[1],__shfl_xor(V[1],S)); \
                      V[2]=fmaxf(V[2],__shfl_xor(V[2],S)); V[3]=fmaxf(V[3],__shfl_xor(V[3],S)); }
#define SUMRED(V,S) { V[0]+=__shfl_xor(V[0],S); V[1]+=__shfl_xor(V[1],S); \
                      V[2]+=__shfl_xor(V[2],S); V[3]+=__shfl_xor(V[3],S); }
#define EXP4(SV) { SV[0]=__expf(SV[0]-mnew[0]); SV[1]=__expf(SV[1]-mnew[1]); \
                   SV[2]=__expf(SV[2]-mnew[2]); SV[3]=__expf(SV[3]-mnew[3]); }
#define PSTORE(SV,CB) { Ph[pw + (CB)*320 + (pr+0)*LDP + fr] = (half_t)SV[0]; \
                        Ph[pw + (CB)*320 + (pr+1)*LDP + fr] = (half_t)SV[1]; \
                        Ph[pw + (CB)*320 + (pr+2)*LDP + fr] = (half_t)SV[2]; \
                        Ph[pw + (CB)*320 + (pr+3)*LDP + fr] = (half_t)SV[3]; }

__global__ __launch_bounds__(256) void attn_flash_mfma(
    float* __restrict__ qy, const float* __restrict__ kv){
  __shared__ half_t Kh[64 * LDQ];    // K tile; also Q staging pre-loop
  __shared__ half_t Vt[64 * LDV];
  __shared__ half_t Ph[4 * 4 * 16 * LDP];
  const int tid = threadIdx.x;
  const int lane = tid & 63, w = tid >> 6;
  const int fr = lane & 15, fg = lane >> 4;
  const int qt = (int)gridDim.x - 1 - (int)blockIdx.x;
  const int h = blockIdx.y, b = blockIdx.z;
  const int g = h >> 2;
  const float* kbase = kv + (size_t)b * T_ * KV_ + g * 64;
  const float* vbase = kbase + 512;
  float* qbase = qy + ((size_t)b * T_ + qt * 64) * DM_ + h * 64;

  const int srow = tid >> 2, sc0 = (tid & 3) * 16;   // Q/K staging coords
  const int vd = tid & 63, vk8 = (tid >> 6) * 8;     // V^T staging coords
  const int arow = (w * 16 + fr) * LDQ;
  const int pw = w * (4 * 16 * LDP);
  const int pr = fg * 4;

  // ---- stage Q through Kh, pull A-frags to registers, then free Kh --------
  {
    const float* src = qbase + (size_t)srow * DM_ + sc0;
    const f32x4 u0 = *(const f32x4*)(src);
    const f32x4 u1 = *(const f32x4*)(src + 4);
    const f32x4 u2 = *(const f32x4*)(src + 8);
    const f32x4 u3 = *(const f32x4*)(src + 12);
    f16x8 h0, h1; CVT8(h0, u0, u1); CVT8(h1, u2, u3);
    *(f16x8*)&Kh[srow * LDQ + sc0] = h0;
    *(f16x8*)&Kh[srow * LDQ + sc0 + 8] = h1;
  }
  __syncthreads();
  const f16x8 aq0 = *(const f16x8*)&Kh[arow + fg * 8];
  const f16x8 aq1 = *(const f16x8*)&Kh[arow + 32 + fg * 8];
  __syncthreads();   // all waves have their Q-frags -> Kh reusable for K

  f32x4 m = {-INFINITY, -INFINITY, -INFINITY, -INFINITY};
  f32x4 l = {0.f, 0.f, 0.f, 0.f};
  f32x4 o0 = {0.f,0.f,0.f,0.f}, o1 = {0.f,0.f,0.f,0.f};
  f32x4 o2 = {0.f,0.f,0.f,0.f}, o3 = {0.f,0.f,0.f,0.f};

  for (int kt = 0; kt <= qt; ++kt){
    // ---- stage K (row-major) and V (transposed) ---------------------------
    {
      const float* src = kbase + (size_t)(kt * 64 + srow) * KV_ + sc0;
      const f32x4 u0 = *(const f32x4*)(src);
      const f32x4 u1 = *(const f32x4*)(src + 4);
      const f32x4 u2 = *(const f32x4*)(src + 8);
      const f32x4 u3 = *(const f32x4*)(src + 12);
      f16x8 h0, h1; CVT8(h0, u0, u1); CVT8(h1, u2, u3);
      *(f16x8*)&Kh[srow * LDQ + sc0] = h0;
      *(f16x8*)&Kh[srow * LDQ + sc0 + 8] = h1;
    }
#pragma unroll
    for (int it = 0; it < 2; ++it){
      const int k0 = vk8 + it * 32;
      const float* src = vbase + (size_t)(kt * 64 + k0) * KV_ + vd;
      f16x8 hv;
      hv[0] = (half_t)src[0];
      hv[1] = (half_t)src[KV_];
      hv[2] = (half_t)src[2 * KV_];
      hv[3] = (half_t)src[3 * KV_];
      hv[4] = (half_t)src[4 * KV_];
      hv[5] = (half_t)src[5 * KV_];
      hv[6] = (half_t)src[6 * KV_];
      hv[7] = (half_t)src[7 * KV_];
      *(f16x8*)&Vt[vd * LDV + k0] = hv;
    }
    __syncthreads();

    // ---- S = Q @ K^T : 8 MFMA ---------------------------------------------
    f32x4 s0 = {0.f,0.f,0.f,0.f}, s1 = {0.f,0.f,0.f,0.f};
    f32x4 s2 = {0.f,0.f,0.f,0.f}, s3 = {0.f,0.f,0.f,0.f};
    {
      const f16x8 b0 = *(const f16x8*)&Kh[(fr     ) * LDQ + fg * 8];
      const f16x8 b1 = *(const f16x8*)&Kh[(fr     ) * LDQ + 32 + fg * 8];
      s0 = __builtin_amdgcn_mfma_f32_16x16x32_f16(aq0, b0, s0, 0, 0, 0);
      s0 = __builtin_amdgcn_mfma_f32_16x16x32_f16(aq1, b1, s0, 0, 0, 0);
    }
    {
      const f16x8 b0 = *(const f16x8*)&Kh[(16 + fr) * LDQ + fg * 8];
      const f16x8 b1 = *(const f16x8*)&Kh[(16 + fr) * LDQ + 32 + fg * 8];
      s1 = __builtin_amdgcn_mfma_f32_16x16x32_f16(aq0, b0, s1, 0, 0, 0);
      s1 = __builtin_amdgcn_mfma_f32_16x16x32_f16(aq1, b1, s1, 0, 0, 0);
    }
    {
      const f16x8 b0 = *(const f16x8*)&Kh[(32 + fr) * LDQ + fg * 8];
      const f16x8 b1 = *(const f16x8*)&Kh[(32 + fr) * LDQ + 32 + fg * 8];
      s2 = __builtin_amdgcn_mfma_f32_16x16x32_f16(aq0, b0, s2, 0, 0, 0);
      s2 = __builtin_amdgcn_mfma_f32_16x16x32_f16(aq1, b1, s2, 0, 0, 0);
    }
    {
      const f16x8 b0 = *(const f16x8*)&Kh[(48 + fr) * LDQ + fg * 8];
      const f16x8 b1 = *(const f16x8*)&Kh[(48 + fr) * LDQ + 32 + fg * 8];
      s3 = __builtin_amdgcn_mfma_f32_16x16x32_f16(aq0, b0, s3, 0, 0, 0);
      s3 = __builtin_amdgcn_mfma_f32_16x16x32_f16(aq1, b1, s3, 0, 0, 0);
    }

    // ---- causal mask (diagonal tile) --------------------------------------
    if (kt == qt){
      const int qr = w * 16 + fg * 4;
      if (fr      > qr    ) s0[0] = -1e30f;
      if (fr      > qr + 1) s0[1] = -1e30f;
      if (fr      > qr + 2) s0[2] = -1e30f;
      if (fr      > qr + 3) s0[3] = -1e30f;
      if (fr + 16 > qr    ) s1[0] = -1e30f;
      if (fr + 16 > qr + 1) s1[1] = -1e30f;
      if (fr + 16 > qr + 2) s1[2] = -1e30f;
      if (fr + 16 > qr + 3) s1[3] = -1e30f;
      if (fr + 32 > qr    ) s2[0] = -1e30f;
      if (fr + 32 > qr + 1) s2[1] = -1e30f;
      if (fr + 32 > qr + 2) s2[2] = -1e30f;
      if (fr + 32 > qr + 3) s2[3] = -1e30f;
      if (fr + 48 > qr    ) s3[0] = -1e30f;
      if (fr + 48 > qr + 1) s3[1] = -1e30f;
      if (fr + 48 > qr + 2) s3[2] = -1e30f;
      if (fr + 48 > qr + 3) s3[3] = -1e30f;
    }

    // ---- online softmax ----------------------------------------------------
    f32x4 vm = VMAX(VMAX(s0, s1), VMAX(s2, s3));
    MAXRED(vm, 1); MAXRED(vm, 2); MAXRED(vm, 4); MAXRED(vm, 8);
    const f32x4 mnew = VMAX(m, vm);
    f32x4 corr;
    corr[0] = __expf(m[0] - mnew[0]);
    corr[1] = __expf(m[1] - mnew[1]);
    corr[2] = __expf(m[2] - mnew[2]);
    corr[3] = __expf(m[3] - mnew[3]);
    EXP4(s0); EXP4(s1); EXP4(s2); EXP4(s3);
    f32x4 rs = s0 + s1 + s2 + s3;
    SUMRED(rs, 1); SUMRED(rs, 2); SUMRED(rs, 4); SUMRED(rs, 8);
    m = mnew;
    l = l * corr + rs;
    o0 *= corr; o1 *= corr; o2 *= corr; o3 *= corr;

    // ---- P -> LDS (same-wave region; DS in-order; no barrier) -------------
    PSTORE(s0, 0); PSTORE(s1, 1); PSTORE(s2, 2); PSTORE(s3, 3);

    // ---- O += P @ V : 8 MFMA ----------------------------------------------
    const f16x8 pa0 = *(const f16x8*)&Ph[pw + ((fg >> 1)    ) * 320 + fr * LDP + (fg & 1) * 8];
    const f16x8 pa1 = *(const f16x8*)&Ph[pw + (2 + (fg >> 1)) * 320 + fr * LDP + (fg & 1) * 8];
    {
      const f16x8 b0 = *(const f16x8*)&Vt[(fr     ) * LDV + fg * 8];
      const f16x8 b1 = *(const f16x8*)&Vt[(fr     ) * LDV + 32 + fg * 8];
      o0 = __builtin_amdgcn_mfma_f32_16x16x32_f16(pa0, b0, o0, 0, 0, 0);
      o0 = __builtin_amdgcn_mfma_f32_16x16x32_f16(pa1, b1, o0, 0, 0, 0);
    }
    {
      const f16x8 b0 = *(const f16x8*)&Vt[(16 + fr) * LDV + fg * 8];
      const f16x8 b1 = *(const f16x8*)&Vt[(16 + fr) * LDV + 32 + fg * 8];
      o1 = __builtin_amdgcn_mfma_f32_16x16x32_f16(pa0, b0, o1, 0, 0, 0);
      o1 = __builtin_amdgcn_mfma_f32_16x16x32_f16(pa1, b1, o1, 0, 0, 0);
    }
    {
      const f16x8 b0 = *(const f16x8*)&Vt[(32 + fr) * LDV + fg * 8];
      const f16x8 b1 = *(const f16x8*)&Vt[(32 + fr) * LDV + 32 + fg * 8];
      o2 = __builtin_amdgcn_mfma_f32_16x16x32_f16(pa0, b0, o2, 0, 0, 0);
      o2 = __builtin_amdgcn_mfma_f32_16x16x32_f16(pa1, b1, o2, 0, 0, 0);
    }
    {
      const f16x8 b0 = *(const f16x8*)&Vt[(48 + fr) * LDV + fg * 8];
      const f16x8 b1 = *(const f16x8*)&Vt[(48 + fr) * LDV + 32 + fg * 8];
      o3 = __builtin_amdgcn_mfma_f32_16x16x32_f16(pa0, b0, o3, 0, 0, 0);
      o3 = __builtin_amdgcn_mfma_f32_16x16x32_f16(pa1, b1, o3, 0, 0, 0);
    }

    __syncthreads();   // all waves done with Kh/Vt -> safe to re-stage
  }

  // ---- epilogue ------------------------------------------------------------
  f32x4 inv;
  inv[0] = 1.f / l[0]; inv[1] = 1.f / l[1];
  inv[2] = 1.f / l[2]; inv[3] = 1.f / l[3];
  o0 *= inv; o1 *= inv; o2 *= inv; o3 *= inv;
  const int orow = w * 16 + fg * 4;
  float* dst = qbase + (size_t)orow * DM_ + fr;
  dst[(size_t)0 * DM_ +  0] = o0[0]; dst[(size_t)1 * DM_ +  0] = o0[1];
  dst[(size_t)2 * DM_ +  0] = o0[2]; dst[(size_t)3 * DM_ +  0] = o0[3];
  dst[(size_t)0 * DM_ + 16] = o1[0]; dst[(size_t)1 * DM_ + 16] = o1[1];
  dst[(size_t)2 * DM_ + 16] = o1[2]; dst[(size_t)3 * DM_ + 16] = o1[3];
  dst[(size_t)0 * DM_ + 32] = o2[0]; dst[(size_t)1 * DM_ + 32] = o2[1];
  dst[(size_t)2 * DM_ + 32] = o2[2]; dst[(size_t)3 * DM_ + 32] = o2[3];
  dst[(size_t)0 * DM_ + 48] = o3[0]; dst[(size_t)1 * DM_ + 48] = o3[1];
  dst[(size_t)2 * DM_ + 48] = o3[2]; dst[(size_t)3 * DM_ + 48] = o3[3];
}

// ---------------------------------------------------------------------------
extern "C" void kernel_launch(void* const* d_in, const int* in_sizes, int n_in,
                              void* d_out, int out_size, void* d_ws, size_t ws_size,
                              hipStream_t stream) {
  const float *x = nullptr, *w_qkv = nullptr, *w_proj = nullptr;
  for (int i = 0; i < n_in; ++i){
    if (in_sizes[i] == 8388608)      x      = (const float*)d_in[i];
    else if (in_sizes[i] == 6291456) w_qkv  = (const float*)d_in[i];
    else if (in_sizes[i] == 4194304) w_proj = (const float*)d_in[i];
  }
  float* out = (float*)d_out;   // reference output dtype is float32

  // ws (50.3 MB): qy f32 @0 (33.5MB) ; kv f32 @33.5MB (16.8MB)
  char* ws = (char*)d_ws;
  float* qy  = (float*)ws;
  float* kvb = (float*)(ws + (size_t)33554432);

  gemm_f16_mfma<<<dim3(24, 32), 256, 0, stream>>>(x, w_qkv, qy, kvb, 3072, 2048);
  rope_qk_f32<<<4096, 256, 0, stream>>>(qy, kvb);
  attn_flash_mfma<<<dim3(32, 32, 2), 256, 0, stream>>>(qy, kvb);
  gemm_f16_mfma<<<dim3(16, 32), 256, 0, stream>>>(qy, w_proj, out, out, 2048, 2048);
}